// Round 3
// baseline (1759.323 us; speedup 1.0000x reference)
//
#include <hip/hip_runtime.h>
#include <cstdint>
#include <cstddef>

#define NN 50000
#define NE 800000
#define NP 50048      // 391*128 padded rows
#define ROWT 391

typedef unsigned short u16;
typedef _Float16 f16;
typedef _Float16 hf8 __attribute__((ext_vector_type(8)));
typedef float f32x4 __attribute__((ext_vector_type(4)));

union U32 { unsigned u; f16 h[2]; };
union U64 { uint2 v; f16 h[4]; };

__device__ __forceinline__ float b2f(u16 v){ return __uint_as_float((unsigned)v << 16); }
__device__ __forceinline__ u16 f2b(float f){
  unsigned u = __float_as_uint(f);
  return (u16)((u + 0x7fffu + ((u >> 16) & 1u)) >> 16);
}
// dtype-agnostic load of float input i (flag: 1 = float32, 0 = bf16)
__device__ __forceinline__ float ldf(const void* p, long i, int f32){
  return f32 ? ((const float*)p)[i] : b2f(((const u16*)p)[i]);
}

// ---------------- dtype detect (bf16 N(0,1) has exp<=~0x81; f32 low-halves are random) ----
__global__ void detect_k(const u16* __restrict__ nf, int* __restrict__ flag)
{
  int mx = 0;
  for (int i = 0; i < 256; ++i) { int e = (nf[i] >> 7) & 0xFF; mx = e > mx ? e : mx; }
  flag[0] = (mx >= 0x90) ? 1 : 0;
}

__global__ void zero_i_k(int* __restrict__ p, int n)
{
  int i = blockIdx.x * 256 + threadIdx.x;
  if (i < n) p[i] = 0;
}

// ---------------- weight prep ----------------
// Wcat[l] = [512 rows(n) x 128(k)] f16 : rows 0-127 Wq^T, 128-255 Wk^T, 256-383 Wv^T,
// rows 384-511 Wqe^T where Wqe[k][h*16+j] = sum_d Wq[k][h*16+d]*eW2[l][j][h*16+d]
__global__ void prep_qkve_k(const void* __restrict__ Wq, const void* __restrict__ Wk,
                            const void* __restrict__ Wv, const void* __restrict__ eW2,
                            f16* __restrict__ Wcat, const int* __restrict__ dflag)
{
  int f32 = dflag[0];
  int idx = blockIdx.x * 256 + threadIdx.x;   // [6][512][128]
  int l = idx >> 16;
  int rem = idx & 65535;
  int r = rem >> 7;        // output row n (gemm col)
  int kk = rem & 127;      // K index
  long base = (long)l * 16384;
  float val;
  if (r < 384) {
    const void* W = (r < 128) ? Wq : (r < 256) ? Wk : Wv;
    int n = r & 127;
    val = ldf(W, base + kk * 128 + n, f32);
  } else {
    int n = r - 384, h = n >> 4, j = n & 15;
    long wq = base + kk * 128 + h * 16;
    long e2 = (long)l * 2048 + j * 128 + h * 16;
    float s = 0.f;
    #pragma unroll
    for (int d = 0; d < 16; ++d) s += ldf(Wq, wq + d, f32) * ldf(eW2, e2 + d, f32);
    val = s;
  }
  Wcat[idx] = (f16)val;
}

// in [6][R][C] -> out [6][C][R] f16 (B^T layout for gemm)
__global__ void transpose_k(const void* __restrict__ in, f16* __restrict__ out, int R, int C,
                            const int* __restrict__ dflag)
{
  int f32 = dflag[0];
  int idx = blockIdx.x * 256 + threadIdx.x;
  int rc = R * C;
  int l = idx / rc, rem = idx % rc;
  int r = rem / C, c = rem % C;
  out[l * rc + c * R + r] = (f16)ldf(in, idx, f32);
}

// ---------------- CSR build ----------------
__global__ void deg_count_k(const int* __restrict__ eidx, int* __restrict__ deg)
{
  int e = blockIdx.x * 256 + threadIdx.x;
  if (e < NE) atomicAdd(&deg[eidx[NE + e]], 1);
}

__global__ void scan_k(const int* __restrict__ deg, int* __restrict__ rstart,
                       int* __restrict__ cursor, int Nn)
{
  __shared__ int sums[1024];
  int t = threadIdx.x;
  int chunk = (Nn + 1023) >> 10;
  int start = t * chunk;
  int end = start + chunk; if (end > Nn) end = Nn;
  int s = 0;
  for (int i = start; i < end; ++i) s += deg[i];
  sums[t] = s;
  __syncthreads();
  for (int o = 1; o < 1024; o <<= 1) {
    int v = (t >= o) ? sums[t - o] : 0;
    __syncthreads();
    sums[t] += v;
    __syncthreads();
  }
  int run = (t == 0) ? 0 : sums[t - 1];
  for (int i = start; i < end; ++i) { rstart[i] = run; cursor[i] = run; run += deg[i]; }
  if (end == Nn && start < Nn) rstart[Nn] = run;
}

__global__ void csr_fill_k(const int* __restrict__ eidx, int* __restrict__ cursor,
                           int* __restrict__ csrc, int* __restrict__ ceid)
{
  int e = blockIdx.x * 256 + threadIdx.x;
  if (e >= NE) return;
  int d = eidx[NE + e];
  int slot = atomicAdd(&cursor[d], 1);
  csrc[slot] = eidx[e];
  ceid[slot] = e;
}

// gather edge attrs into CSR slot order, 4 f16 per slot (8B aligned)
__global__ void ea_gather_k(const void* __restrict__ eatt, const int* __restrict__ ceid,
                            f16* __restrict__ ea4, const int* __restrict__ dflag)
{
  int f32 = dflag[0];
  int e = blockIdx.x * 256 + threadIdx.x;
  if (e >= NE) return;
  long id = ceid[e];
  f16* q = ea4 + (size_t)e * 4;
  q[0] = (f16)ldf(eatt, id * 3 + 0, f32);
  q[1] = (f16)ldf(eatt, id * 3 + 1, f32);
  q[2] = (f16)ldf(eatt, id * 3 + 2, f32);
  q[3] = (f16)0.f;
}

// ---------------- embedding (covers padded rows with zeros) ----------------
__global__ void emb_k(const void* __restrict__ nf, const void* __restrict__ embW,
                      const void* __restrict__ embB, float* __restrict__ xf,
                      f16* __restrict__ xh, const int* __restrict__ dflag)
{
  int f32 = dflag[0];
  int idx = blockIdx.x * 256 + threadIdx.x;   // NP*128 exact
  int node = idx >> 7, c = idx & 127;
  float s = 0.f;
  if (node < NN) {
    s = ldf(embB, c, f32);
    long row = (long)node * 20;
    #pragma unroll
    for (int f = 0; f < 20; ++f) s += ldf(nf, row + f, f32) * ldf(embW, f * 128 + c, f32);
  }
  xf[idx] = s;
  xh[idx] = (f16)s;
}

// ---------------- MFMA GEMM: C = A[M,K] @ B (given as Bt[N,K]), 128x128 tile ----------------
// MODE 0: 4 f16 outputs (q,k,v,qe), ld 128, no bias. grid (391,4)
// MODE 1: f16 out (hb), ld 512, bias + relu. grid (391,4)
// MODE 2: f16 out (ffh), ld 128, bias. grid (391,1)
template<int MODE>
__global__ __launch_bounds__(256)
void gemm_k(const f16* __restrict__ A, const f16* __restrict__ Bt, int K,
            f16* __restrict__ o0, f16* __restrict__ o1, f16* __restrict__ o2, f16* __restrict__ o3,
            const void* __restrict__ bias, int boff, const int* __restrict__ dflag)
{
  __shared__ __align__(16) f16 lA[128 * 32];
  __shared__ __align__(16) f16 lB[128 * 32];
  const int tid = threadIdx.x;
  const int wave = tid >> 6, lane = tid & 63;
  const int wr = wave >> 1, wc = wave & 1;
  const size_t rowBase = (size_t)blockIdx.x * 128;
  const size_t colBase = (size_t)blockIdx.y * 128;
  const int m = lane & 15, q4 = lane >> 4;   // mfma lane coords

  f32x4 zero = {0.f, 0.f, 0.f, 0.f};
  f32x4 acc[4][4];
  #pragma unroll
  for (int i = 0; i < 4; ++i)
    #pragma unroll
    for (int j = 0; j < 4; ++j) acc[i][j] = zero;

  // staging: wave stages rows [wave*32, wave*32+32); lane = lr*4+lq covers (row lr & lr+16, 16B chunk lq)
  const int lr = lane >> 2, lq = lane & 3;
  const f16* Ap = A + (rowBase + wave * 32 + lr) * (size_t)K + lq * 8;
  const f16* Bp = Bt + (colBase + wave * 32 + lr) * (size_t)K + lq * 8;
  uint4* sA = (uint4*)(lA + wave * 1024) + lane;  // lane*16B; +64 -> +1024B (rows 16..31)
  uint4* sB = (uint4*)(lB + wave * 1024) + lane;

  uint4 a0 = *(const uint4*)(Ap);
  uint4 a1 = *(const uint4*)(Ap + (size_t)16 * K);
  uint4 b0 = *(const uint4*)(Bp);
  uint4 b1 = *(const uint4*)(Bp + (size_t)16 * K);

  for (int k0 = 0; k0 < K; k0 += 32) {
    sA[0] = a0; sA[64] = a1;
    sB[0] = b0; sB[64] = b1;
    __syncthreads();
    if (k0 + 32 < K) {
      a0 = *(const uint4*)(Ap + k0 + 32);
      a1 = *(const uint4*)(Ap + k0 + 32 + (size_t)16 * K);
      b0 = *(const uint4*)(Bp + k0 + 32);
      b1 = *(const uint4*)(Bp + k0 + 32 + (size_t)16 * K);
    }
    hf8 af[4], bf[4];
    #pragma unroll
    for (int i = 0; i < 4; ++i) af[i] = *(const hf8*)(lA + (wr * 64 + i * 16 + m) * 32 + q4 * 8);
    #pragma unroll
    for (int j = 0; j < 4; ++j) bf[j] = *(const hf8*)(lB + (wc * 64 + j * 16 + m) * 32 + q4 * 8);
    #pragma unroll
    for (int i = 0; i < 4; ++i)
      #pragma unroll
      for (int j = 0; j < 4; ++j)
        acc[i][j] = __builtin_amdgcn_mfma_f32_16x16x32_f16(af[i], bf[j], acc[i][j], 0, 0, 0);
    __syncthreads();
  }

  // C/D layout: col = lane&15 (m), row = q4*4 + reg  (verified m89/m91)
  if (MODE == 0) {
    f16* o = (blockIdx.y == 0) ? o0 : (blockIdx.y == 1) ? o1 : (blockIdx.y == 2) ? o2 : o3;
    #pragma unroll
    for (int i = 0; i < 4; ++i)
      #pragma unroll
      for (int r = 0; r < 4; ++r) {
        size_t row = rowBase + wr * 64 + i * 16 + q4 * 4 + r;
        #pragma unroll
        for (int j = 0; j < 4; ++j) {
          int col = wc * 64 + j * 16 + m;
          o[row * 128 + col] = (f16)acc[i][j][r];
        }
      }
  } else if (MODE == 1) {
    int f32 = dflag[0];
    #pragma unroll
    for (int j = 0; j < 4; ++j) {
      int colg = (int)colBase + wc * 64 + j * 16 + m;
      float bv = ldf(bias, boff + colg, f32);
      #pragma unroll
      for (int i = 0; i < 4; ++i)
        #pragma unroll
        for (int r = 0; r < 4; ++r) {
          size_t row = rowBase + wr * 64 + i * 16 + q4 * 4 + r;
          float v = acc[i][j][r] + bv;
          o0[row * 512 + colg] = (f16)fmaxf(v, 0.f);
        }
    }
  } else {
    int f32 = dflag[0];
    #pragma unroll
    for (int j = 0; j < 4; ++j) {
      int colg = wc * 64 + j * 16 + m;
      float bv = ldf(bias, boff + colg, f32);
      #pragma unroll
      for (int i = 0; i < 4; ++i)
        #pragma unroll
        for (int r = 0; r < 4; ++r) {
          size_t row = rowBase + wr * 64 + i * 16 + q4 * 4 + r;
          o0[row * 128 + colg] = (f16)(acc[i][j][r] + bv);
        }
    }
  }
}

// ---------------- edge attention + scatter + LN1 (one wave per dst node) ----------------
__global__ void edge_k(const f16* __restrict__ qf, const f16* __restrict__ kf,
                       const f16* __restrict__ vf, const f16* __restrict__ qef,
                       const f16* __restrict__ ea4,
                       const int* __restrict__ rstart, const int* __restrict__ csrc,
                       const void* __restrict__ eW1, int oW1,
                       const void* __restrict__ eb1, int ob1,
                       const void* __restrict__ eb2, int ob2,
                       const void* __restrict__ g, const void* __restrict__ bp, int olg,
                       float* __restrict__ xf, f16* __restrict__ xh,
                       const int* __restrict__ dflag)
{
  int f32 = dflag[0];
  int wave = threadIdx.x >> 6, lane = threadIdx.x & 63;
  int node = blockIdx.x * 4 + wave;
  if (node >= NN) return;
  int c0 = lane << 1;       // 2 channels per lane; head = lane>>3, t = lane&7 covers d=2t,2t+1
  int t = lane & 7;
  size_t nb = (size_t)node * 128 + c0;

  U32 u;
  u.u = *(const unsigned*)(qf + nb);
  float q0 = (float)u.h[0], q1 = (float)u.h[1];
  u.u = *(const unsigned*)(qef + nb);
  float qe0 = (float)u.h[0], qe1 = (float)u.h[1];

  // per-head q.eb2 (reduce over the 8 lanes of this head)
  float pb = q0 * ldf(eb2, ob2 + c0, f32) + q1 * ldf(eb2, ob2 + c0 + 1, f32);
  pb += __shfl_xor(pb, 1); pb += __shfl_xor(pb, 2); pb += __shfl_xor(pb, 4);

  // edge-MLP first-layer columns for this lane's j0=2t, j1=2t+1 (same for all heads)
  int j0 = t << 1;
  float w00 = ldf(eW1, oW1 + j0, f32),      w01 = ldf(eW1, oW1 + j0 + 1, f32);
  float w10 = ldf(eW1, oW1 + 16 + j0, f32), w11 = ldf(eW1, oW1 + 16 + j0 + 1, f32);
  float w20 = ldf(eW1, oW1 + 32 + j0, f32), w21 = ldf(eW1, oW1 + 32 + j0 + 1, f32);
  float bb0 = ldf(eb1, ob1 + j0, f32), bb1 = ldf(eb1, ob1 + j0 + 1, f32);

  float acc0 = 0.f, acc1 = 0.f;
  int e0 = rstart[node], e1 = rstart[node + 1];
  for (int e = e0; e < e1; ++e) {
    int s = csrc[e];
    U64 ue; ue.v = *(const uint2*)(ea4 + (size_t)e * 4);
    float a0 = (float)ue.h[0], a1 = (float)ue.h[1], a2 = (float)ue.h[2];
    float h0 = fmaxf(fmaf(a2, w20, fmaf(a1, w10, fmaf(a0, w00, bb0))), 0.f);
    float h1 = fmaxf(fmaf(a2, w21, fmaf(a1, w11, fmaf(a0, w01, bb1))), 0.f);
    size_t sb = (size_t)s * 128 + c0;
    U32 uk; uk.u = *(const unsigned*)(kf + sb);
    U32 uv; uv.u = *(const unsigned*)(vf + sb);
    float p = q0 * (float)uk.h[0] + q1 * (float)uk.h[1] + qe0 * h0 + qe1 * h1;
    p += __shfl_xor(p, 1); p += __shfl_xor(p, 2); p += __shfl_xor(p, 4);
    float logit = (p + pb) * 0.25f;
    // softmax over the 8 heads (lane bits 3..5)
    float mx = logit;
    mx = fmaxf(mx, __shfl_xor(mx, 8)); mx = fmaxf(mx, __shfl_xor(mx, 16)); mx = fmaxf(mx, __shfl_xor(mx, 32));
    float ex = __expf(logit - mx);
    float se = ex;
    se += __shfl_xor(se, 8); se += __shfl_xor(se, 16); se += __shfl_xor(se, 32);
    float w = ex / se;
    acc0 = fmaf(w, (float)uv.h[0], acc0);
    acc1 = fmaf(w, (float)uv.h[1], acc1);
  }

  // x = LN(x + agg)
  float y0 = xf[nb] + acc0, y1 = xf[nb + 1] + acc1;
  float s1 = y0 + y1, s2 = y0 * y0 + y1 * y1;
  #pragma unroll
  for (int o = 1; o < 64; o <<= 1) { s1 += __shfl_xor(s1, o); s2 += __shfl_xor(s2, o); }
  float mu = s1 * 0.0078125f;
  float var = s2 * 0.0078125f - mu * mu;
  float rstd = rsqrtf(var + 1e-5f);
  float o0v = (y0 - mu) * rstd * ldf(g, olg + c0, f32) + ldf(bp, olg + c0, f32);
  float o1v = (y1 - mu) * rstd * ldf(g, olg + c0 + 1, f32) + ldf(bp, olg + c0 + 1, f32);
  xf[nb] = o0v; xf[nb + 1] = o1v;
  U32 wz; wz.h[0] = (f16)o0v; wz.h[1] = (f16)o1v;
  *(unsigned*)(xh + nb) = wz.u;
}

// ---------------- residual + LN2 (one wave per node) ----------------
__global__ void ln_res_k(const f16* __restrict__ add, float* __restrict__ xf,
                         f16* __restrict__ xh, const void* __restrict__ g,
                         const void* __restrict__ bp, int olg, const int* __restrict__ dflag)
{
  int f32 = dflag[0];
  int wave = threadIdx.x >> 6, lane = threadIdx.x & 63;
  int node = blockIdx.x * 4 + wave;
  if (node >= NN) return;
  int c0 = lane << 1;
  size_t nb = (size_t)node * 128 + c0;
  U32 ua; ua.u = *(const unsigned*)(add + nb);
  float y0 = xf[nb] + (float)ua.h[0];
  float y1 = xf[nb + 1] + (float)ua.h[1];
  float s1 = y0 + y1, s2 = y0 * y0 + y1 * y1;
  #pragma unroll
  for (int o = 1; o < 64; o <<= 1) { s1 += __shfl_xor(s1, o); s2 += __shfl_xor(s2, o); }
  float mu = s1 * 0.0078125f;
  float var = s2 * 0.0078125f - mu * mu;
  float rstd = rsqrtf(var + 1e-5f);
  float o0v = (y0 - mu) * rstd * ldf(g, olg + c0, f32) + ldf(bp, olg + c0, f32);
  float o1v = (y1 - mu) * rstd * ldf(g, olg + c0 + 1, f32) + ldf(bp, olg + c0 + 1, f32);
  xf[nb] = o0v; xf[nb + 1] = o1v;
  U32 wz; wz.h[0] = (f16)o0v; wz.h[1] = (f16)o1v;
  *(unsigned*)(xh + nb) = wz.u;
}

__global__ void out_k(const float* __restrict__ xf, void* __restrict__ out,
                      const int* __restrict__ dflag)
{
  int f32 = dflag[0];
  int idx = blockIdx.x * 256 + threadIdx.x;   // NN*128 exact
  if (f32) ((float*)out)[idx] = xf[idx];
  else     ((u16*)out)[idx] = f2b(xf[idx]);
}

// ---------------- launch ----------------
extern "C" void kernel_launch(void* const* d_in, const int* in_sizes, int n_in,
                              void* d_out, int out_size, void* d_ws, size_t ws_size,
                              hipStream_t stream)
{
  const void* nf   = d_in[0];
  const void* eatt = d_in[1];
  const int*  eidx = (const int*)d_in[2];
  const void* embW = d_in[3];
  const void* embB = d_in[4];
  const void* Wq   = d_in[5];
  const void* Wk   = d_in[6];
  const void* Wv   = d_in[7];
  const void* eW1  = d_in[8];
  const void* eb1  = d_in[9];
  const void* eW2  = d_in[10];
  const void* eb2  = d_in[11];
  const void* lng  = d_in[12];
  const void* lnb  = d_in[13];
  const void* fW1  = d_in[14];
  const void* fb1  = d_in[15];
  const void* fW2  = d_in[16];
  const void* fb2  = d_in[17];

  char* p = (char*)d_ws;
  auto alloc = [&](size_t b) { char* r = p; p += (b + 255) & ~(size_t)255; return r; };
  int* dflag = (int*)alloc(256);
  float* xf  = (float*)alloc((size_t)NP * 128 * 4);
  f16*   xh  = (f16*)  alloc((size_t)NP * 128 * 2);
  int* deg   = (int*)alloc((NN + 1) * 4);
  int* rst   = (int*)alloc((NN + 1) * 4);
  int* cur   = (int*)alloc((size_t)NN * 4);
  int* csrc  = (int*)alloc((size_t)NE * 4);
  f16* ea4   = (f16*)alloc((size_t)NE * 4 * 2);
  f16* Wcat  = (f16*)alloc((size_t)6 * 512 * 128 * 2);
  f16* W1t   = (f16*)alloc((size_t)6 * 512 * 128 * 2);
  f16* W2t   = (f16*)alloc((size_t)6 * 128 * 512 * 2);
  // layer scratch: edge phase uses q/k/v/qe (4 x NP*128 f16);
  // ff phase uses hb (NP*512 f16) + ffh (NP*128 f16)
  char* S    = alloc((size_t)NP * 512 * 2 + (size_t)NP * 128 * 2);
  f16* qf = (f16*)S;
  f16* kf = qf + (size_t)NP * 128;
  f16* vf = kf + (size_t)NP * 128;
  f16* qe = vf + (size_t)NP * 128;
  f16* hb = (f16*)S;
  f16* ffh = hb + (size_t)NP * 512;
  int* ceid = (int*)S;   // build-phase only; S reused afterwards

  detect_k<<<1, 1, 0, stream>>>((const u16*)nf, dflag);
  prep_qkve_k<<<1536, 256, 0, stream>>>(Wq, Wk, Wv, eW2, Wcat, dflag);
  transpose_k<<<1536, 256, 0, stream>>>(fW1, W1t, 128, 512, dflag);
  transpose_k<<<1536, 256, 0, stream>>>(fW2, W2t, 512, 128, dflag);
  zero_i_k<<<(NN + 256) / 256, 256, 0, stream>>>(deg, NN + 1);
  deg_count_k<<<3125, 256, 0, stream>>>(eidx, deg);
  scan_k<<<1, 1024, 0, stream>>>(deg, rst, cur, NN);
  csr_fill_k<<<3125, 256, 0, stream>>>(eidx, cur, csrc, ceid);
  ea_gather_k<<<3125, 256, 0, stream>>>(eatt, ceid, ea4, dflag);
  emb_k<<<NP * 128 / 256, 256, 0, stream>>>(nf, embW, embB, xf, xh, dflag);

  for (int l = 0; l < 6; ++l) {
    gemm_k<0><<<dim3(ROWT, 4), 256, 0, stream>>>(xh, Wcat + (size_t)l * 65536, 128,
                                                 qf, kf, vf, qe, nullptr, 0, dflag);
    edge_k<<<12500, 256, 0, stream>>>(qf, kf, vf, qe, ea4, rst, csrc,
                                      eW1, l * 48, eb1, l * 16, eb2, l * 128,
                                      lng, lnb, l * 128, xf, xh, dflag);
    gemm_k<1><<<dim3(ROWT, 4), 256, 0, stream>>>(xh, W1t + (size_t)l * 65536, 128,
                                                 hb, nullptr, nullptr, nullptr, fb1, l * 512, dflag);
    gemm_k<2><<<dim3(ROWT, 1), 256, 0, stream>>>(hb, W2t + (size_t)l * 65536, 512,
                                                 ffh, nullptr, nullptr, nullptr, fb2, l * 128, dflag);
    ln_res_k<<<12500, 256, 0, stream>>>(ffh, xf, xh, lng, lnb, l * 128, dflag);
  }
  out_k<<<25000, 256, 0, stream>>>(xf, d_out, dflag);
}

// Round 4
// 1585.798 us; speedup vs baseline: 1.1094x; 1.1094x over previous
//
#include <hip/hip_runtime.h>
#include <cstdint>
#include <cstddef>

#define NN 50000
#define NE 800000
#define NP 50048      // 391*128 padded rows
#define ROWT 391

typedef unsigned short u16;
typedef _Float16 f16;
typedef _Float16 hf8 __attribute__((ext_vector_type(8)));
typedef float f32x4 __attribute__((ext_vector_type(4)));

union U32 { unsigned u; f16 h[2]; };
union U64 { uint2 v; f16 h[4]; };

__device__ __forceinline__ float b2f(u16 v){ return __uint_as_float((unsigned)v << 16); }
__device__ __forceinline__ u16 f2b(float f){
  unsigned u = __float_as_uint(f);
  return (u16)((u + 0x7fffu + ((u >> 16) & 1u)) >> 16);
}
// dtype-agnostic load of float input i (flag: 1 = float32, 0 = bf16)
__device__ __forceinline__ float ldf(const void* p, long i, int f32){
  return f32 ? ((const float*)p)[i] : b2f(((const u16*)p)[i]);
}

// ---------------- dtype detect (bf16 N(0,1) has exp<=~0x81; f32 low-halves are random) ----
__global__ void detect_k(const u16* __restrict__ nf, int* __restrict__ flag)
{
  int mx = 0;
  for (int i = 0; i < 256; ++i) { int e = (nf[i] >> 7) & 0xFF; mx = e > mx ? e : mx; }
  flag[0] = (mx >= 0x90) ? 1 : 0;
}

__global__ void zero_i_k(int* __restrict__ p, int n)
{
  int i = blockIdx.x * 256 + threadIdx.x;
  if (i < n) p[i] = 0;
}

// ---------------- weight prep ----------------
// Wcat[l] = [512 rows(n) x 128(k)] f16 : rows 0-127 Wq^T, 128-255 Wk^T, 256-383 Wv^T,
// rows 384-511 Wqe^T where Wqe[k][h*16+j] = sum_d Wq[k][h*16+d]*eW2[l][j][h*16+d]
__global__ void prep_qkve_k(const void* __restrict__ Wq, const void* __restrict__ Wk,
                            const void* __restrict__ Wv, const void* __restrict__ eW2,
                            f16* __restrict__ Wcat, const int* __restrict__ dflag)
{
  int f32 = dflag[0];
  int idx = blockIdx.x * 256 + threadIdx.x;   // [6][512][128]
  int l = idx >> 16;
  int rem = idx & 65535;
  int r = rem >> 7;        // output row n (gemm col)
  int kk = rem & 127;      // K index
  long base = (long)l * 16384;
  float val;
  if (r < 384) {
    const void* W = (r < 128) ? Wq : (r < 256) ? Wk : Wv;
    int n = r & 127;
    val = ldf(W, base + kk * 128 + n, f32);
  } else {
    int n = r - 384, h = n >> 4, j = n & 15;
    long wq = base + kk * 128 + h * 16;
    long e2 = (long)l * 2048 + j * 128 + h * 16;
    float s = 0.f;
    #pragma unroll
    for (int d = 0; d < 16; ++d) s += ldf(Wq, wq + d, f32) * ldf(eW2, e2 + d, f32);
    val = s;
  }
  Wcat[idx] = (f16)val;
}

// in [6][R][C] -> out [6][C][R] f16 (B^T layout for gemm)
__global__ void transpose_k(const void* __restrict__ in, f16* __restrict__ out, int R, int C,
                            const int* __restrict__ dflag)
{
  int f32 = dflag[0];
  int idx = blockIdx.x * 256 + threadIdx.x;
  int rc = R * C;
  int l = idx / rc, rem = idx % rc;
  int r = rem / C, c = rem % C;
  out[l * rc + c * R + r] = (f16)ldf(in, idx, f32);
}

// ---------------- CSR build ----------------
__global__ void deg_count_k(const int* __restrict__ eidx, int* __restrict__ deg)
{
  int e = blockIdx.x * 256 + threadIdx.x;
  if (e < NE) atomicAdd(&deg[eidx[NE + e]], 1);
}

__global__ void scan_k(const int* __restrict__ deg, int* __restrict__ rstart,
                       int* __restrict__ cursor, int Nn)
{
  __shared__ int sums[1024];
  int t = threadIdx.x;
  int chunk = (Nn + 1023) >> 10;
  int start = t * chunk;
  int end = start + chunk; if (end > Nn) end = Nn;
  int s = 0;
  for (int i = start; i < end; ++i) s += deg[i];
  sums[t] = s;
  __syncthreads();
  for (int o = 1; o < 1024; o <<= 1) {
    int v = (t >= o) ? sums[t - o] : 0;
    __syncthreads();
    sums[t] += v;
    __syncthreads();
  }
  int run = (t == 0) ? 0 : sums[t - 1];
  for (int i = start; i < end; ++i) { rstart[i] = run; cursor[i] = run; run += deg[i]; }
  if (end == Nn && start < Nn) rstart[Nn] = run;
}

__global__ void csr_fill_k(const int* __restrict__ eidx, int* __restrict__ cursor,
                           int* __restrict__ csrc, int* __restrict__ ceid)
{
  int e = blockIdx.x * 256 + threadIdx.x;
  if (e >= NE) return;
  int d = eidx[NE + e];
  int slot = atomicAdd(&cursor[d], 1);
  csrc[slot] = eidx[e];
  ceid[slot] = e;
}

// gather edge attrs into CSR slot order, 4 f16 per slot (8B aligned)
__global__ void ea_gather_k(const void* __restrict__ eatt, const int* __restrict__ ceid,
                            f16* __restrict__ ea4, const int* __restrict__ dflag)
{
  int f32 = dflag[0];
  int e = blockIdx.x * 256 + threadIdx.x;
  if (e >= NE) return;
  long id = ceid[e];
  f16* q = ea4 + (size_t)e * 4;
  q[0] = (f16)ldf(eatt, id * 3 + 0, f32);
  q[1] = (f16)ldf(eatt, id * 3 + 1, f32);
  q[2] = (f16)ldf(eatt, id * 3 + 2, f32);
  q[3] = (f16)0.f;
}

// ---------------- embedding (covers padded rows with zeros) ----------------
__global__ void emb_k(const void* __restrict__ nf, const void* __restrict__ embW,
                      const void* __restrict__ embB, float* __restrict__ xf,
                      f16* __restrict__ xh, const int* __restrict__ dflag)
{
  int f32 = dflag[0];
  int idx = blockIdx.x * 256 + threadIdx.x;   // NP*128 exact
  int node = idx >> 7, c = idx & 127;
  float s = 0.f;
  if (node < NN) {
    s = ldf(embB, c, f32);
    long row = (long)node * 20;
    #pragma unroll
    for (int f = 0; f < 20; ++f) s += ldf(nf, row + f, f32) * ldf(embW, f * 128 + c, f32);
  }
  xf[idx] = s;
  xh[idx] = (f16)s;
}

// ---------------- MFMA GEMM: C = A[M,K] @ B (given as Bt[N,K]), 128x128 tile ----------------
// MODE 0: q -> o0 (ld128), k -> o1 cols 0-127 of ld256, v -> o1 cols 128-255, qe -> o3. grid (391,4)
// MODE 1: f16 out (hb), ld 512, bias + relu. grid (391,4)
// MODE 2: f16 out (ffh), ld 128, bias. grid (391,1)
template<int MODE>
__global__ __launch_bounds__(256)
void gemm_k(const f16* __restrict__ A, const f16* __restrict__ Bt, int K,
            f16* __restrict__ o0, f16* __restrict__ o1, f16* __restrict__ o3,
            const void* __restrict__ bias, int boff, const int* __restrict__ dflag)
{
  __shared__ __align__(16) f16 lA[128 * 32];
  __shared__ __align__(16) f16 lB[128 * 32];
  const int tid = threadIdx.x;
  const int wave = tid >> 6, lane = tid & 63;
  const int wr = wave >> 1, wc = wave & 1;
  const size_t rowBase = (size_t)blockIdx.x * 128;
  const size_t colBase = (size_t)blockIdx.y * 128;
  const int m = lane & 15, q4 = lane >> 4;   // mfma lane coords

  f32x4 zero = {0.f, 0.f, 0.f, 0.f};
  f32x4 acc[4][4];
  #pragma unroll
  for (int i = 0; i < 4; ++i)
    #pragma unroll
    for (int j = 0; j < 4; ++j) acc[i][j] = zero;

  // staging: wave stages rows [wave*32, wave*32+32); lane = lr*4+lq covers (row lr & lr+16, 16B chunk lq)
  const int lr = lane >> 2, lq = lane & 3;
  const f16* Ap = A + (rowBase + wave * 32 + lr) * (size_t)K + lq * 8;
  const f16* Bp = Bt + (colBase + wave * 32 + lr) * (size_t)K + lq * 8;
  uint4* sA = (uint4*)(lA + wave * 1024) + lane;  // lane*16B; +64 -> +1024B (rows 16..31)
  uint4* sB = (uint4*)(lB + wave * 1024) + lane;

  uint4 a0 = *(const uint4*)(Ap);
  uint4 a1 = *(const uint4*)(Ap + (size_t)16 * K);
  uint4 b0 = *(const uint4*)(Bp);
  uint4 b1 = *(const uint4*)(Bp + (size_t)16 * K);

  for (int k0 = 0; k0 < K; k0 += 32) {
    sA[0] = a0; sA[64] = a1;
    sB[0] = b0; sB[64] = b1;
    __syncthreads();
    if (k0 + 32 < K) {
      a0 = *(const uint4*)(Ap + k0 + 32);
      a1 = *(const uint4*)(Ap + k0 + 32 + (size_t)16 * K);
      b0 = *(const uint4*)(Bp + k0 + 32);
      b1 = *(const uint4*)(Bp + k0 + 32 + (size_t)16 * K);
    }
    hf8 af[4], bf[4];
    #pragma unroll
    for (int i = 0; i < 4; ++i) af[i] = *(const hf8*)(lA + (wr * 64 + i * 16 + m) * 32 + q4 * 8);
    #pragma unroll
    for (int j = 0; j < 4; ++j) bf[j] = *(const hf8*)(lB + (wc * 64 + j * 16 + m) * 32 + q4 * 8);
    #pragma unroll
    for (int i = 0; i < 4; ++i)
      #pragma unroll
      for (int j = 0; j < 4; ++j)
        acc[i][j] = __builtin_amdgcn_mfma_f32_16x16x32_f16(af[i], bf[j], acc[i][j], 0, 0, 0);
    __syncthreads();
  }

  // C/D layout: col = lane&15 (m), row = q4*4 + reg  (verified m89/m91)
  if (MODE == 0) {
    // q -> o0 ld128; k -> o1+0 ld256; v -> o1+128 ld256; qe -> o3 ld128
    f16* o; size_t ld; int off;
    if (blockIdx.y == 0)      { o = o0; ld = 128; off = 0; }
    else if (blockIdx.y == 1) { o = o1; ld = 256; off = 0; }
    else if (blockIdx.y == 2) { o = o1; ld = 256; off = 128; }
    else                      { o = o3; ld = 128; off = 0; }
    #pragma unroll
    for (int i = 0; i < 4; ++i)
      #pragma unroll
      for (int r = 0; r < 4; ++r) {
        size_t row = rowBase + wr * 64 + i * 16 + q4 * 4 + r;
        #pragma unroll
        for (int j = 0; j < 4; ++j) {
          int col = wc * 64 + j * 16 + m;
          o[row * ld + off + col] = (f16)acc[i][j][r];
        }
      }
  } else if (MODE == 1) {
    int f32 = dflag[0];
    #pragma unroll
    for (int j = 0; j < 4; ++j) {
      int colg = (int)colBase + wc * 64 + j * 16 + m;
      float bv = ldf(bias, boff + colg, f32);
      #pragma unroll
      for (int i = 0; i < 4; ++i)
        #pragma unroll
        for (int r = 0; r < 4; ++r) {
          size_t row = rowBase + wr * 64 + i * 16 + q4 * 4 + r;
          float v = acc[i][j][r] + bv;
          o0[row * 512 + colg] = (f16)fmaxf(v, 0.f);
        }
    }
  } else {
    int f32 = dflag[0];
    #pragma unroll
    for (int j = 0; j < 4; ++j) {
      int colg = wc * 64 + j * 16 + m;
      float bv = ldf(bias, boff + colg, f32);
      #pragma unroll
      for (int i = 0; i < 4; ++i)
        #pragma unroll
        for (int r = 0; r < 4; ++r) {
          size_t row = rowBase + wr * 64 + i * 16 + q4 * 4 + r;
          o0[row * 128 + colg] = (f16)(acc[i][j][r] + bv);
        }
    }
  }
}

// ---------------- edge attention + scatter + LN1 ----------------
// One wave per dst node; TWO edges in flight (32 lanes each, 4 channels/lane).
// lane: sub = lane>>5 (edge slot), l = lane&31, c0 = l*4, head = l>>2, t = l&3.
// Dot-reduce within head: shfl 1,2. Head-softmax: shfl 4,8,16 (intra-half).
__global__ void edge_k(const f16* __restrict__ qf, const f16* __restrict__ kv,
                       const f16* __restrict__ qef,
                       const f16* __restrict__ ea4,
                       const int* __restrict__ rstart, const int* __restrict__ csrc,
                       const void* __restrict__ eW1, int oW1,
                       const void* __restrict__ eb1, int ob1,
                       const void* __restrict__ eb2, int ob2,
                       const void* __restrict__ g, const void* __restrict__ bp, int olg,
                       float* __restrict__ xf, f16* __restrict__ xh,
                       const int* __restrict__ dflag)
{
  int f32 = dflag[0];
  int wave = threadIdx.x >> 6, lane = threadIdx.x & 63;
  int node = blockIdx.x * 4 + wave;
  if (node >= NN) return;
  int sub = lane >> 5, l = lane & 31;
  int c0 = l << 2;          // 4 channels per lane
  int t = l & 3;            // MLP hidden cols j0 = t*4 .. t*4+3
  size_t nb = (size_t)node * 128 + c0;

  float q[4], qe[4];
  { U64 u; u.v = *(const uint2*)(qf + nb);
    #pragma unroll
    for (int i = 0; i < 4; ++i) q[i] = (float)u.h[i];
    u.v = *(const uint2*)(qef + nb);
    #pragma unroll
    for (int i = 0; i < 4; ++i) qe[i] = (float)u.h[i]; }

  // per-head q.eb2 (reduce over the 4 lanes of this head)
  float pb = 0.f;
  #pragma unroll
  for (int i = 0; i < 4; ++i) pb += q[i] * ldf(eb2, ob2 + c0 + i, f32);
  pb += __shfl_xor(pb, 1); pb += __shfl_xor(pb, 2);

  // edge-MLP first-layer weights for cols j0..j0+3 (same for all heads)
  int j0 = t << 2;
  float w0[4], w1[4], w2[4], bb[4];
  #pragma unroll
  for (int i = 0; i < 4; ++i) {
    w0[i] = ldf(eW1, oW1 + j0 + i, f32);
    w1[i] = ldf(eW1, oW1 + 16 + j0 + i, f32);
    w2[i] = ldf(eW1, oW1 + 32 + j0 + i, f32);
    bb[i] = ldf(eb1, ob1 + j0 + i, f32);
  }

  float acc[4] = {0.f, 0.f, 0.f, 0.f};
  int e0 = rstart[node], e1 = rstart[node + 1];

  int e = e0 + sub;
  int sN = 0; uint2 eaN = {0, 0}, kN = {0, 0}, vN = {0, 0};
  if (e < e1) {
    sN = csrc[e];
    eaN = *(const uint2*)(ea4 + (size_t)e * 4);
    size_t kb = (size_t)sN * 256 + c0;
    kN = *(const uint2*)(kv + kb);
    vN = *(const uint2*)(kv + kb + 128);
  }
  for (; e < e1; e += 2) {
    uint2 eaC = eaN, kC = kN, vC = vN;
    int en = e + 2;
    if (en < e1) {
      sN = csrc[en];
      eaN = *(const uint2*)(ea4 + (size_t)en * 4);
      size_t kb = (size_t)sN * 256 + c0;
      kN = *(const uint2*)(kv + kb);
      vN = *(const uint2*)(kv + kb + 128);
    }
    U64 ue; ue.v = eaC;
    float a0 = (float)ue.h[0], a1 = (float)ue.h[1], a2 = (float)ue.h[2];
    float p = 0.f;
    U64 uk; uk.v = kC;
    U64 uv; uv.v = vC;
    #pragma unroll
    for (int i = 0; i < 4; ++i) {
      float h = fmaxf(fmaf(a2, w2[i], fmaf(a1, w1[i], fmaf(a0, w0[i], bb[i]))), 0.f);
      p = fmaf(q[i], (float)uk.h[i], fmaf(qe[i], h, p));
    }
    p += __shfl_xor(p, 1); p += __shfl_xor(p, 2);
    float logit = (p + pb) * 0.25f;
    // softmax over the 8 heads (lane bits 2..4 of l)
    float mx = logit;
    mx = fmaxf(mx, __shfl_xor(mx, 4)); mx = fmaxf(mx, __shfl_xor(mx, 8)); mx = fmaxf(mx, __shfl_xor(mx, 16));
    float ex = __expf(logit - mx);
    float se = ex;
    se += __shfl_xor(se, 4); se += __shfl_xor(se, 8); se += __shfl_xor(se, 16);
    float w = ex / se;
    #pragma unroll
    for (int i = 0; i < 4; ++i) acc[i] = fmaf(w, (float)uv.h[i], acc[i]);
  }

  // combine the two edge slots
  #pragma unroll
  for (int i = 0; i < 4; ++i) acc[i] += __shfl_xor(acc[i], 32);

  // x = LN(x + agg)   (both halves hold all 128 channels; reduce within 32 lanes)
  float4 xo = *(const float4*)(xf + nb);
  float y[4] = { xo.x + acc[0], xo.y + acc[1], xo.z + acc[2], xo.w + acc[3] };
  float s1 = y[0] + y[1] + y[2] + y[3];
  float s2 = y[0]*y[0] + y[1]*y[1] + y[2]*y[2] + y[3]*y[3];
  #pragma unroll
  for (int o = 1; o < 32; o <<= 1) { s1 += __shfl_xor(s1, o); s2 += __shfl_xor(s2, o); }
  float mu = s1 * 0.0078125f;
  float var = s2 * 0.0078125f - mu * mu;
  float rstd = rsqrtf(var + 1e-5f);
  float ov[4];
  #pragma unroll
  for (int i = 0; i < 4; ++i)
    ov[i] = (y[i] - mu) * rstd * ldf(g, olg + c0 + i, f32) + ldf(bp, olg + c0 + i, f32);
  if (sub == 0) {
    float4 st = { ov[0], ov[1], ov[2], ov[3] };
    *(float4*)(xf + nb) = st;
    U64 wz;
    #pragma unroll
    for (int i = 0; i < 4; ++i) wz.h[i] = (f16)ov[i];
    *(uint2*)(xh + nb) = wz.v;
  }
}

// ---------------- residual + LN2 (one wave per node) ----------------
__global__ void ln_res_k(const f16* __restrict__ add, float* __restrict__ xf,
                         f16* __restrict__ xh, const void* __restrict__ g,
                         const void* __restrict__ bp, int olg, const int* __restrict__ dflag)
{
  int f32 = dflag[0];
  int wave = threadIdx.x >> 6, lane = threadIdx.x & 63;
  int node = blockIdx.x * 4 + wave;
  if (node >= NN) return;
  int c0 = lane << 1;
  size_t nb = (size_t)node * 128 + c0;
  U32 ua; ua.u = *(const unsigned*)(add + nb);
  float y0 = xf[nb] + (float)ua.h[0];
  float y1 = xf[nb + 1] + (float)ua.h[1];
  float s1 = y0 + y1, s2 = y0 * y0 + y1 * y1;
  #pragma unroll
  for (int o = 1; o < 64; o <<= 1) { s1 += __shfl_xor(s1, o); s2 += __shfl_xor(s2, o); }
  float mu = s1 * 0.0078125f;
  float var = s2 * 0.0078125f - mu * mu;
  float rstd = rsqrtf(var + 1e-5f);
  float o0v = (y0 - mu) * rstd * ldf(g, olg + c0, f32) + ldf(bp, olg + c0, f32);
  float o1v = (y1 - mu) * rstd * ldf(g, olg + c0 + 1, f32) + ldf(bp, olg + c0 + 1, f32);
  xf[nb] = o0v; xf[nb + 1] = o1v;
  U32 wz; wz.h[0] = (f16)o0v; wz.h[1] = (f16)o1v;
  *(unsigned*)(xh + nb) = wz.u;
}

__global__ void out_k(const float* __restrict__ xf, void* __restrict__ out,
                      const int* __restrict__ dflag)
{
  int f32 = dflag[0];
  int idx = blockIdx.x * 256 + threadIdx.x;   // NN*128 exact
  if (f32) ((float*)out)[idx] = xf[idx];
  else     ((u16*)out)[idx] = f2b(xf[idx]);
}

// ---------------- launch ----------------
extern "C" void kernel_launch(void* const* d_in, const int* in_sizes, int n_in,
                              void* d_out, int out_size, void* d_ws, size_t ws_size,
                              hipStream_t stream)
{
  const void* nf   = d_in[0];
  const void* eatt = d_in[1];
  const int*  eidx = (const int*)d_in[2];
  const void* embW = d_in[3];
  const void* embB = d_in[4];
  const void* Wq   = d_in[5];
  const void* Wk   = d_in[6];
  const void* Wv   = d_in[7];
  const void* eW1  = d_in[8];
  const void* eb1  = d_in[9];
  const void* eW2  = d_in[10];
  const void* eb2  = d_in[11];
  const void* lng  = d_in[12];
  const void* lnb  = d_in[13];
  const void* fW1  = d_in[14];
  const void* fb1  = d_in[15];
  const void* fW2  = d_in[16];
  const void* fb2  = d_in[17];

  char* p = (char*)d_ws;
  auto alloc = [&](size_t b) { char* r = p; p += (b + 255) & ~(size_t)255; return r; };
  int* dflag = (int*)alloc(256);
  float* xf  = (float*)alloc((size_t)NP * 128 * 4);
  f16*   xh  = (f16*)  alloc((size_t)NP * 128 * 2);
  int* deg   = (int*)alloc((NN + 1) * 4);
  int* rst   = (int*)alloc((NN + 1) * 4);
  int* cur   = (int*)alloc((size_t)NN * 4);
  int* csrc  = (int*)alloc((size_t)NE * 4);
  f16* ea4   = (f16*)alloc((size_t)NE * 4 * 2);
  f16* Wcat  = (f16*)alloc((size_t)6 * 512 * 128 * 2);
  f16* W1t   = (f16*)alloc((size_t)6 * 512 * 128 * 2);
  f16* W2t   = (f16*)alloc((size_t)6 * 128 * 512 * 2);
  // layer scratch: edge phase uses q (NP*128) + qe (NP*128) + kv interleaved (NP*256);
  // ff phase uses hb (NP*512 f16) + ffh (NP*128 f16)
  char* S    = alloc((size_t)NP * 512 * 2 + (size_t)NP * 128 * 2);
  f16* qf = (f16*)S;
  f16* qe = qf + (size_t)NP * 128;
  f16* kv = qe + (size_t)NP * 128;   // [node][256]: k cols 0-127, v cols 128-255
  f16* hb = (f16*)S;
  f16* ffh = hb + (size_t)NP * 512;
  int* ceid = (int*)S;   // build-phase only; S reused afterwards

  detect_k<<<1, 1, 0, stream>>>((const u16*)nf, dflag);
  prep_qkve_k<<<1536, 256, 0, stream>>>(Wq, Wk, Wv, eW2, Wcat, dflag);
  transpose_k<<<1536, 256, 0, stream>>>(fW1, W1t, 128, 512, dflag);
  transpose_k<<<1536, 256, 0, stream>>>(fW2, W2t, 512, 128, dflag);
  zero_i_k<<<(NN + 256) / 256, 256, 0, stream>>>(deg, NN + 1);
  deg_count_k<<<3125, 256, 0, stream>>>(eidx, deg);
  scan_k<<<1, 1024, 0, stream>>>(deg, rst, cur, NN);
  csr_fill_k<<<3125, 256, 0, stream>>>(eidx, cur, csrc, ceid);
  ea_gather_k<<<3125, 256, 0, stream>>>(eatt, ceid, ea4, dflag);
  emb_k<<<NP * 128 / 256, 256, 0, stream>>>(nf, embW, embB, xf, xh, dflag);

  for (int l = 0; l < 6; ++l) {
    gemm_k<0><<<dim3(ROWT, 4), 256, 0, stream>>>(xh, Wcat + (size_t)l * 65536, 128,
                                                 qf, kv, qe, nullptr, 0, dflag);
    edge_k<<<12500, 256, 0, stream>>>(qf, kv, qe, ea4, rst, csrc,
                                      eW1, l * 48, eb1, l * 16, eb2, l * 128,
                                      lng, lnb, l * 128, xf, xh, dflag);
    gemm_k<1><<<dim3(ROWT, 4), 256, 0, stream>>>(xh, W1t + (size_t)l * 65536, 128,
                                                 hb, nullptr, nullptr, fb1, l * 512, dflag);
    gemm_k<2><<<dim3(ROWT, 1), 256, 0, stream>>>(hb, W2t + (size_t)l * 65536, 512,
                                                 ffh, nullptr, nullptr, fb2, l * 128, dflag);
    ln_res_k<<<12500, 256, 0, stream>>>(ffh, xf, xh, lng, lnb, l * 128, dflag);
  }
  out_k<<<25000, 256, 0, stream>>>(xf, d_out, dflag);
}

// Round 5
// 1517.230 us; speedup vs baseline: 1.1596x; 1.0452x over previous
//
#include <hip/hip_runtime.h>
#include <cstdint>
#include <cstddef>

#define NN 50000
#define NE 800000
#define NP 50048      // 391*128 padded rows
#define ROWT 391

typedef unsigned short u16;
typedef _Float16 f16;
typedef _Float16 hf8 __attribute__((ext_vector_type(8)));
typedef float f32x4 __attribute__((ext_vector_type(4)));

union U32 { unsigned u; f16 h[2]; };
union U64 { uint2 v; f16 h[4]; };
union U128 { uint4 v; f16 x[8]; };

__device__ __forceinline__ float b2f(u16 v){ return __uint_as_float((unsigned)v << 16); }
__device__ __forceinline__ u16 f2b(float f){
  unsigned u = __float_as_uint(f);
  return (u16)((u + 0x7fffu + ((u >> 16) & 1u)) >> 16);
}
// dtype-agnostic load of float input i (flag: 1 = float32, 0 = bf16)
__device__ __forceinline__ float ldf(const void* p, long i, int f32){
  return f32 ? ((const float*)p)[i] : b2f(((const u16*)p)[i]);
}
__device__ __forceinline__ void gl_lds16(const void* g, void* l){
  __builtin_amdgcn_global_load_lds((const __attribute__((address_space(1))) void*)g,
                                   (__attribute__((address_space(3))) void*)l, 16, 0, 0);
}

// ---------------- dtype detect (bf16 N(0,1) has exp<=~0x81; f32 low-halves are random) ----
__global__ void detect_k(const u16* __restrict__ nf, int* __restrict__ flag)
{
  int mx = 0;
  for (int i = 0; i < 256; ++i) { int e = (nf[i] >> 7) & 0xFF; mx = e > mx ? e : mx; }
  flag[0] = (mx >= 0x90) ? 1 : 0;
}

__global__ void zero_i_k(int* __restrict__ p, int n)
{
  int i = blockIdx.x * 256 + threadIdx.x;
  if (i < n) p[i] = 0;
}

// ---------------- small-param f32 conversion table ----------------
// layout (floats): eW1[6*48]@0, eb1[6*16]@288, eb2[6*128]@384, lng[6*128]@1152,
// lnb[6*128]@1920, fb1[6*512]@2688, fb2[6*128]@5760, embB[128]@6528, embW[2560]@6656 ; total 9216
__global__ void conv_k(const void* eW1, const void* eb1, const void* eb2,
                       const void* lng, const void* lnb, const void* fb1, const void* fb2,
                       const void* embB, const void* embW,
                       float* __restrict__ pf, const int* __restrict__ dflag)
{
  int f32 = dflag[0];
  int i = blockIdx.x * 256 + threadIdx.x;
  if (i >= 9216) return;
  const void* p; long off;
  if (i < 288)       { p = eW1;  off = i; }
  else if (i < 384)  { p = eb1;  off = i - 288; }
  else if (i < 1152) { p = eb2;  off = i - 384; }
  else if (i < 1920) { p = lng;  off = i - 1152; }
  else if (i < 2688) { p = lnb;  off = i - 1920; }
  else if (i < 5760) { p = fb1;  off = i - 2688; }
  else if (i < 6528) { p = fb2;  off = i - 5760; }
  else if (i < 6656) { p = embB; off = i - 6528; }
  else               { p = embW; off = i - 6656; }
  pf[i] = ldf(p, off, f32);
}

// ---------------- weight prep ----------------
// Wcat[l] = [512 rows(n) x 128(k)] f16 : rows 0-127 Wq^T, 128-255 Wk^T, 256-383 Wv^T,
// rows 384-511 Wqe^T where Wqe[k][h*16+j] = sum_d Wq[k][h*16+d]*eW2[l][j][h*16+d]
__global__ void prep_qkve_k(const void* __restrict__ Wq, const void* __restrict__ Wk,
                            const void* __restrict__ Wv, const void* __restrict__ eW2,
                            f16* __restrict__ Wcat, const int* __restrict__ dflag)
{
  int f32 = dflag[0];
  int idx = blockIdx.x * 256 + threadIdx.x;   // [6][512][128]
  int l = idx >> 16;
  int rem = idx & 65535;
  int r = rem >> 7;
  int kk = rem & 127;
  long base = (long)l * 16384;
  float val;
  if (r < 384) {
    const void* W = (r < 128) ? Wq : (r < 256) ? Wk : Wv;
    int n = r & 127;
    val = ldf(W, base + kk * 128 + n, f32);
  } else {
    int n = r - 384, h = n >> 4, j = n & 15;
    long wq = base + kk * 128 + h * 16;
    long e2 = (long)l * 2048 + j * 128 + h * 16;
    float s = 0.f;
    #pragma unroll
    for (int d = 0; d < 16; ++d) s += ldf(Wq, wq + d, f32) * ldf(eW2, e2 + d, f32);
    val = s;
  }
  Wcat[idx] = (f16)val;
}

// in [6][R][C] -> out [6][C][R] f16 (B^T layout for gemm)
__global__ void transpose_k(const void* __restrict__ in, f16* __restrict__ out, int R, int C,
                            const int* __restrict__ dflag)
{
  int f32 = dflag[0];
  int idx = blockIdx.x * 256 + threadIdx.x;
  int rc = R * C;
  int l = idx / rc, rem = idx % rc;
  int r = rem / C, c = rem % C;
  out[l * rc + c * R + r] = (f16)ldf(in, idx, f32);
}

// ---------------- CSR build ----------------
__global__ void deg_count_k(const int* __restrict__ eidx, int* __restrict__ deg)
{
  int e = blockIdx.x * 256 + threadIdx.x;
  if (e < NE) atomicAdd(&deg[eidx[NE + e]], 1);
}

__global__ void scan_k(const int* __restrict__ deg, int* __restrict__ rstart,
                       int* __restrict__ cursor, int Nn)
{
  __shared__ int sums[1024];
  int t = threadIdx.x;
  int chunk = (Nn + 1023) >> 10;
  int start = t * chunk;
  int end = start + chunk; if (end > Nn) end = Nn;
  int s = 0;
  for (int i = start; i < end; ++i) s += deg[i];
  sums[t] = s;
  __syncthreads();
  for (int o = 1; o < 1024; o <<= 1) {
    int v = (t >= o) ? sums[t - o] : 0;
    __syncthreads();
    sums[t] += v;
    __syncthreads();
  }
  int run = (t == 0) ? 0 : sums[t - 1];
  for (int i = start; i < end; ++i) { rstart[i] = run; cursor[i] = run; run += deg[i]; }
  if (end == Nn && start < Nn) rstart[Nn] = run;
}

__global__ void csr_fill_k(const int* __restrict__ eidx, int* __restrict__ cursor,
                           int* __restrict__ csrc, int* __restrict__ cdst,
                           int* __restrict__ ceid)
{
  int e = blockIdx.x * 256 + threadIdx.x;
  if (e >= NE) return;
  int d = eidx[NE + e];
  int slot = atomicAdd(&cursor[d], 1);
  csrc[slot] = eidx[e];
  cdst[slot] = d;
  ceid[slot] = e;
}

// gather edge attrs into CSR slot order, 4 f16 per slot (8B aligned)
__global__ void ea_gather_k(const void* __restrict__ eatt, const int* __restrict__ ceid,
                            f16* __restrict__ ea4, const int* __restrict__ dflag)
{
  int f32 = dflag[0];
  int e = blockIdx.x * 256 + threadIdx.x;
  if (e >= NE) return;
  long id = ceid[e];
  f16* q = ea4 + (size_t)e * 4;
  q[0] = (f16)ldf(eatt, id * 3 + 0, f32);
  q[1] = (f16)ldf(eatt, id * 3 + 1, f32);
  q[2] = (f16)ldf(eatt, id * 3 + 2, f32);
  q[3] = (f16)0.f;
}

// ---------------- embedding (covers padded rows with zeros) ----------------
__global__ void emb_k(const void* __restrict__ nf, const float* __restrict__ embWf,
                      const float* __restrict__ embBf, float* __restrict__ xf,
                      f16* __restrict__ xh, const int* __restrict__ dflag)
{
  int f32 = dflag[0];
  int idx = blockIdx.x * 256 + threadIdx.x;   // NP*128 exact
  int node = idx >> 7, c = idx & 127;
  float s = 0.f;
  if (node < NN) {
    s = embBf[c];
    long row = (long)node * 20;
    #pragma unroll
    for (int f = 0; f < 20; ++f) s += ldf(nf, row + f, f32) * embWf[f * 128 + c];
  }
  xf[idx] = s;
  xh[idx] = (f16)s;
}

// ---------------- MFMA GEMM: C = A[M,K] @ B (given as Bt[N,K]), 128x128 tile ----------------
// global_load_lds width-16 staging (m97 pattern), layout identical to verified explicit version.
// MODE 0: q -> o0 (ld128), k -> o1 cols 0-127 of ld256, v -> o1 cols 128-255, qe -> o3. grid (391,4)
// MODE 1: f16 out (hb), ld 512, bias + relu. grid (391,4)
// MODE 2: f16 out (ffh), ld 128, bias. grid (391,1)
template<int MODE>
__global__ __launch_bounds__(256)
void gemm_k(const f16* __restrict__ A, const f16* __restrict__ Bt, int K,
            f16* __restrict__ o0, f16* __restrict__ o1, f16* __restrict__ o3,
            const float* __restrict__ bias)
{
  __shared__ __align__(16) f16 lA[128 * 32];
  __shared__ __align__(16) f16 lB[128 * 32];
  const int tid = threadIdx.x;
  const int wave = tid >> 6, lane = tid & 63;
  const int wr = wave >> 1, wc = wave & 1;
  const size_t rowBase = (size_t)blockIdx.x * 128;
  const size_t colBase = (size_t)blockIdx.y * 128;
  const int m = lane & 15, q4 = lane >> 4;

  f32x4 zero = {0.f, 0.f, 0.f, 0.f};
  f32x4 acc[4][4];
  #pragma unroll
  for (int i = 0; i < 4; ++i)
    #pragma unroll
    for (int j = 0; j < 4; ++j) acc[i][j] = zero;

  // staging: wave stages rows [wave*32, wave*32+32); LDS dest = wave-uniform base + lane*16B
  const int lr = lane >> 2, lq = lane & 3;
  const f16* Ap = A + (rowBase + wave * 32 + lr) * (size_t)K + lq * 8;
  const f16* Bp = Bt + (colBase + wave * 32 + lr) * (size_t)K + lq * 8;
  f16* lAp = lA + wave * 1024;
  f16* lBp = lB + wave * 1024;

  for (int k0 = 0; k0 < K; k0 += 32) {
    gl_lds16(Ap + k0, lAp);
    gl_lds16(Ap + k0 + (size_t)16 * K, lAp + 512);
    gl_lds16(Bp + k0, lBp);
    gl_lds16(Bp + k0 + (size_t)16 * K, lBp + 512);
    __syncthreads();
    hf8 af[4], bf[4];
    #pragma unroll
    for (int i = 0; i < 4; ++i) af[i] = *(const hf8*)(lA + (wr * 64 + i * 16 + m) * 32 + q4 * 8);
    #pragma unroll
    for (int j = 0; j < 4; ++j) bf[j] = *(const hf8*)(lB + (wc * 64 + j * 16 + m) * 32 + q4 * 8);
    #pragma unroll
    for (int i = 0; i < 4; ++i)
      #pragma unroll
      for (int j = 0; j < 4; ++j)
        acc[i][j] = __builtin_amdgcn_mfma_f32_16x16x32_f16(af[i], bf[j], acc[i][j], 0, 0, 0);
    __syncthreads();
  }

  if (MODE == 0) {
    f16* o; size_t ld; int off;
    if (blockIdx.y == 0)      { o = o0; ld = 128; off = 0; }
    else if (blockIdx.y == 1) { o = o1; ld = 256; off = 0; }
    else if (blockIdx.y == 2) { o = o1; ld = 256; off = 128; }
    else                      { o = o3; ld = 128; off = 0; }
    #pragma unroll
    for (int i = 0; i < 4; ++i)
      #pragma unroll
      for (int r = 0; r < 4; ++r) {
        size_t row = rowBase + wr * 64 + i * 16 + q4 * 4 + r;
        #pragma unroll
        for (int j = 0; j < 4; ++j) {
          int col = wc * 64 + j * 16 + m;
          o[row * ld + off + col] = (f16)acc[i][j][r];
        }
      }
  } else if (MODE == 1) {
    #pragma unroll
    for (int j = 0; j < 4; ++j) {
      int colg = (int)colBase + wc * 64 + j * 16 + m;
      float bv = bias[colg];
      #pragma unroll
      for (int i = 0; i < 4; ++i)
        #pragma unroll
        for (int r = 0; r < 4; ++r) {
          size_t row = rowBase + wr * 64 + i * 16 + q4 * 4 + r;
          o0[row * 512 + colg] = (f16)fmaxf(acc[i][j][r] + bv, 0.f);
        }
    }
  } else {
    #pragma unroll
    for (int j = 0; j < 4; ++j) {
      int colg = wc * 64 + j * 16 + m;
      float bv = bias[colg];
      #pragma unroll
      for (int i = 0; i < 4; ++i)
        #pragma unroll
        for (int r = 0; r < 4; ++r) {
          size_t row = rowBase + wr * 64 + i * 16 + q4 * 4 + r;
          o0[row * 128 + colg] = (f16)(acc[i][j][r] + bv);
        }
    }
  }
}

// ---------------- per-(node,head) bias: pb = q . eb2 ----------------
__global__ void pb_k(const f16* __restrict__ qf, const float* __restrict__ eb2f,
                     float* __restrict__ pbt)
{
  int idx = blockIdx.x * 256 + threadIdx.x;
  if (idx >= NN * 8) return;
  int n = idx >> 3, h = idx & 7;
  U128 a, b;
  a.v = *(const uint4*)(qf + (size_t)n * 128 + h * 16);
  b.v = *(const uint4*)(qf + (size_t)n * 128 + h * 16 + 8);
  const float* e = eb2f + h * 16;
  float p = 0.f;
  #pragma unroll
  for (int d = 0; d < 8; ++d) p = fmaf((float)a.x[d], e[d], fmaf((float)b.x[d], e[8 + d], p));
  pbt[idx] = p;
}

// ---------------- edge-parallel attention weights: one LANE per edge ----------------
// In-register softmax over 8 heads; zero cross-lane ops. Writes w8[e][8] f16 (16B coalesced).
__global__ __launch_bounds__(256)
void attn_k(const f16* __restrict__ qf, const f16* __restrict__ kv, const f16* __restrict__ qef,
            const f16* __restrict__ ea4, const int* __restrict__ csrc, const int* __restrict__ cdst,
            const float* __restrict__ pbt, const float* __restrict__ eW1f,
            const float* __restrict__ eb1f, f16* __restrict__ w8)
{
  int e = blockIdx.x * 256 + threadIdx.x;
  if (e >= NE) return;
  int src = csrc[e], dst = cdst[e];
  U64 ue; ue.v = *(const uint2*)(ea4 + (size_t)e * 4);
  float a0 = (float)ue.h[0], a1 = (float)ue.h[1], a2 = (float)ue.h[2];
  float he[16];
  #pragma unroll
  for (int j = 0; j < 16; ++j)
    he[j] = fmaxf(fmaf(a2, eW1f[32 + j], fmaf(a1, eW1f[16 + j], fmaf(a0, eW1f[j], eb1f[j]))), 0.f);
  const uint4* qr = (const uint4*)(qf + (size_t)dst * 128);
  const uint4* kr = (const uint4*)(kv + (size_t)src * 256);
  const uint4* er = (const uint4*)(qef + (size_t)dst * 128);
  float4 pb0 = *(const float4*)(pbt + (size_t)dst * 8);
  float4 pb1 = *(const float4*)(pbt + (size_t)dst * 8 + 4);
  float pbv[8] = { pb0.x, pb0.y, pb0.z, pb0.w, pb1.x, pb1.y, pb1.z, pb1.w };
  float logit[8];
  uint4 qa = qr[0], qb = qr[1], ka = kr[0], kb = kr[1], za = er[0], zb = er[1];
  #pragma unroll
  for (int h = 0; h < 8; ++h) {
    uint4 qa2, qb2, ka2, kb2, za2, zb2;
    if (h < 7) {
      qa2 = qr[2*h+2]; qb2 = qr[2*h+3];
      ka2 = kr[2*h+2]; kb2 = kr[2*h+3];
      za2 = er[2*h+2]; zb2 = er[2*h+3];
    }
    U128 Q0, Q1, K0, K1, E0, E1;
    Q0.v = qa; Q1.v = qb; K0.v = ka; K1.v = kb; E0.v = za; E1.v = zb;
    float p = 0.f;
    #pragma unroll
    for (int d = 0; d < 8; ++d) {
      p = fmaf((float)Q0.x[d], (float)K0.x[d], p);
      p = fmaf((float)Q1.x[d], (float)K1.x[d], p);
      p = fmaf((float)E0.x[d], he[d], p);
      p = fmaf((float)E1.x[d], he[8 + d], p);
    }
    logit[h] = (p + pbv[h]) * 0.25f;
    qa = qa2; qb = qb2; ka = ka2; kb = kb2; za = za2; zb = zb2;
  }
  float mx = logit[0];
  #pragma unroll
  for (int h = 1; h < 8; ++h) mx = fmaxf(mx, logit[h]);
  float se = 0.f, ex[8];
  #pragma unroll
  for (int h = 0; h < 8; ++h) { ex[h] = __expf(logit[h] - mx); se += ex[h]; }
  float inv = 1.f / se;
  U128 W;
  #pragma unroll
  for (int h = 0; h < 8; ++h) W.x[h] = (f16)(ex[h] * inv);
  *(uint4*)(w8 + (size_t)e * 8) = W.v;
}

// ---------------- aggregation + residual + LN1 ----------------
// One wave per node; 4 edges in flight (16 lanes x 8 channels each); no per-edge shfls.
__global__ void agg_k(const f16* __restrict__ kv, const f16* __restrict__ w8,
                      const int* __restrict__ rstart, const int* __restrict__ csrc,
                      const float* __restrict__ gf, const float* __restrict__ bpf,
                      float* __restrict__ xf, f16* __restrict__ xh)
{
  int wave = threadIdx.x >> 6, lane = threadIdx.x & 63;
  int node = blockIdx.x * 4 + wave;
  if (node >= NN) return;
  int sub = lane >> 4, l = lane & 15;
  int c0 = l << 3;
  int head = l >> 1;
  float acc[8] = {0.f, 0.f, 0.f, 0.f, 0.f, 0.f, 0.f, 0.f};
  int e0 = rstart[node], e1 = rstart[node + 1];
  int e = e0 + sub;
  uint4 vN = {0, 0, 0, 0}; float wN = 0.f;
  if (e < e1) {
    int s = csrc[e];
    vN = *(const uint4*)(kv + (size_t)s * 256 + 128 + c0);
    wN = (float)w8[(size_t)e * 8 + head];
  }
  for (; e < e1; e += 4) {
    uint4 vC = vN; float wC = wN;
    int en = e + 4;
    if (en < e1) {
      int s = csrc[en];
      vN = *(const uint4*)(kv + (size_t)s * 256 + 128 + c0);
      wN = (float)w8[(size_t)en * 8 + head];
    }
    U128 V; V.v = vC;
    #pragma unroll
    for (int i = 0; i < 8; ++i) acc[i] = fmaf(wC, (float)V.x[i], acc[i]);
  }
  #pragma unroll
  for (int i = 0; i < 8; ++i) {
    acc[i] += __shfl_xor(acc[i], 16);
    acc[i] += __shfl_xor(acc[i], 32);
  }
  // LN over 128 channels held by 16 lanes (all 4 sub-groups identical)
  size_t nb = (size_t)node * 128 + c0;
  float4 x0 = *(const float4*)(xf + nb);
  float4 x1 = *(const float4*)(xf + nb + 4);
  float y[8] = { x0.x + acc[0], x0.y + acc[1], x0.z + acc[2], x0.w + acc[3],
                 x1.x + acc[4], x1.y + acc[5], x1.z + acc[6], x1.w + acc[7] };
  float s1 = 0.f, s2 = 0.f;
  #pragma unroll
  for (int i = 0; i < 8; ++i) { s1 += y[i]; s2 += y[i] * y[i]; }
  #pragma unroll
  for (int o = 1; o < 16; o <<= 1) { s1 += __shfl_xor(s1, o); s2 += __shfl_xor(s2, o); }
  float mu = s1 * 0.0078125f;
  float var = s2 * 0.0078125f - mu * mu;
  float rstd = rsqrtf(var + 1e-5f);
  float ov[8];
  #pragma unroll
  for (int i = 0; i < 8; ++i) ov[i] = (y[i] - mu) * rstd * gf[c0 + i] + bpf[c0 + i];
  if (sub == 0) {
    float4 s0 = { ov[0], ov[1], ov[2], ov[3] };
    float4 s1v = { ov[4], ov[5], ov[6], ov[7] };
    *(float4*)(xf + nb) = s0;
    *(float4*)(xf + nb + 4) = s1v;
    U128 wz;
    #pragma unroll
    for (int i = 0; i < 8; ++i) wz.x[i] = (f16)ov[i];
    *(uint4*)(xh + nb) = wz.v;
  }
}

// ---------------- residual + LN2 (one wave per node) ----------------
__global__ void ln_res_k(const f16* __restrict__ add, float* __restrict__ xf,
                         f16* __restrict__ xh, const float* __restrict__ gf,
                         const float* __restrict__ bpf)
{
  int wave = threadIdx.x >> 6, lane = threadIdx.x & 63;
  int node = blockIdx.x * 4 + wave;
  if (node >= NN) return;
  int c0 = lane << 1;
  size_t nb = (size_t)node * 128 + c0;
  U32 ua; ua.u = *(const unsigned*)(add + nb);
  float y0 = xf[nb] + (float)ua.h[0];
  float y1 = xf[nb + 1] + (float)ua.h[1];
  float s1 = y0 + y1, s2 = y0 * y0 + y1 * y1;
  #pragma unroll
  for (int o = 1; o < 64; o <<= 1) { s1 += __shfl_xor(s1, o); s2 += __shfl_xor(s2, o); }
  float mu = s1 * 0.0078125f;
  float var = s2 * 0.0078125f - mu * mu;
  float rstd = rsqrtf(var + 1e-5f);
  float o0v = (y0 - mu) * rstd * gf[c0] + bpf[c0];
  float o1v = (y1 - mu) * rstd * gf[c0 + 1] + bpf[c0 + 1];
  xf[nb] = o0v; xf[nb + 1] = o1v;
  U32 wz; wz.h[0] = (f16)o0v; wz.h[1] = (f16)o1v;
  *(unsigned*)(xh + nb) = wz.u;
}

__global__ void out_k(const float* __restrict__ xf, void* __restrict__ out,
                      const int* __restrict__ dflag)
{
  int f32 = dflag[0];
  int idx = blockIdx.x * 256 + threadIdx.x;   // NN*128 exact
  if (f32) ((float*)out)[idx] = xf[idx];
  else     ((u16*)out)[idx] = f2b(xf[idx]);
}

// ---------------- launch ----------------
extern "C" void kernel_launch(void* const* d_in, const int* in_sizes, int n_in,
                              void* d_out, int out_size, void* d_ws, size_t ws_size,
                              hipStream_t stream)
{
  const void* nf   = d_in[0];
  const void* eatt = d_in[1];
  const int*  eidx = (const int*)d_in[2];
  const void* embW = d_in[3];
  const void* embB = d_in[4];
  const void* Wq   = d_in[5];
  const void* Wk   = d_in[6];
  const void* Wv   = d_in[7];
  const void* eW1  = d_in[8];
  const void* eb1  = d_in[9];
  const void* eW2  = d_in[10];
  const void* eb2  = d_in[11];
  const void* lng  = d_in[12];
  const void* lnb  = d_in[13];
  const void* fW1  = d_in[14];
  const void* fb1  = d_in[15];
  const void* fW2  = d_in[16];
  const void* fb2  = d_in[17];

  char* p = (char*)d_ws;
  auto alloc = [&](size_t b) { char* r = p; p += (b + 255) & ~(size_t)255; return r; };
  int* dflag   = (int*)alloc(256);
  float* pf    = (float*)alloc(9216 * 4);
  float* xf    = (float*)alloc((size_t)NP * 128 * 4);
  f16*   xh    = (f16*)  alloc((size_t)NP * 128 * 2);
  int* deg     = (int*)alloc((NN + 1) * 4);
  int* rst     = (int*)alloc((NN + 1) * 4);
  int* cur     = (int*)alloc((size_t)NN * 4);
  int* csrc    = (int*)alloc((size_t)NE * 4);
  int* cdst    = (int*)alloc((size_t)NE * 4);
  float* pbt   = (float*)alloc((size_t)NN * 8 * 4);
  f16* ea4     = (f16*)alloc((size_t)NE * 4 * 2);
  f16* Wcat    = (f16*)alloc((size_t)6 * 512 * 128 * 2);
  f16* W1t     = (f16*)alloc((size_t)6 * 512 * 128 * 2);
  f16* W2t     = (f16*)alloc((size_t)6 * 128 * 512 * 2);
  // layer scratch S (64MB): edge phase = qf(12.8) + qe(12.8) + kv(25.6) + w8(12.8 in ffh slot);
  // ff phase = hb(51.2) + ffh(12.8). w8 aliases ffh (disjoint in time).
  char* S    = alloc((size_t)NP * 512 * 2 + (size_t)NP * 128 * 2);
  f16* qf  = (f16*)S;
  f16* qe  = qf + (size_t)NP * 128;
  f16* kv  = qe + (size_t)NP * 128;   // [node][256]: k cols 0-127, v cols 128-255
  f16* hb  = (f16*)S;
  f16* ffh = hb + (size_t)NP * 512;
  f16* w8  = ffh;                      // NE*8 f16 = 12.8MB <= 12.81MB slot
  int* ceid = (int*)S;                 // build phase only

  // param table offsets
  float* eW1f = pf;          // +l*48
  float* eb1f = pf + 288;    // +l*16
  float* eb2f = pf + 384;    // +l*128
  float* lngf = pf + 1152;   // +l*128
  float* lnbf = pf + 1920;   // +l*128
  float* fb1f = pf + 2688;   // +l*512
  float* fb2f = pf + 5760;   // +l*128
  float* embBf = pf + 6528;
  float* embWf = pf + 6656;

  detect_k<<<1, 1, 0, stream>>>((const u16*)nf, dflag);
  conv_k<<<36, 256, 0, stream>>>(eW1, eb1, eb2, lng, lnb, fb1, fb2, embB, embW, pf, dflag);
  prep_qkve_k<<<1536, 256, 0, stream>>>(Wq, Wk, Wv, eW2, Wcat, dflag);
  transpose_k<<<1536, 256, 0, stream>>>(fW1, W1t, 128, 512, dflag);
  transpose_k<<<1536, 256, 0, stream>>>(fW2, W2t, 512, 128, dflag);
  zero_i_k<<<(NN + 256) / 256, 256, 0, stream>>>(deg, NN + 1);
  deg_count_k<<<3125, 256, 0, stream>>>(eidx, deg);
  scan_k<<<1, 1024, 0, stream>>>(deg, rst, cur, NN);
  csr_fill_k<<<3125, 256, 0, stream>>>(eidx, cur, csrc, cdst, ceid);
  ea_gather_k<<<3125, 256, 0, stream>>>(eatt, ceid, ea4, dflag);
  emb_k<<<NP * 128 / 256, 256, 0, stream>>>(nf, embWf, embBf, xf, xh, dflag);

  for (int l = 0; l < 6; ++l) {
    gemm_k<0><<<dim3(ROWT, 4), 256, 0, stream>>>(xh, Wcat + (size_t)l * 65536, 128,
                                                 qf, kv, qe, nullptr);
    pb_k<<<(NN * 8 + 255) / 256, 256, 0, stream>>>(qf, eb2f + l * 128, pbt);
    attn_k<<<3125, 256, 0, stream>>>(qf, kv, qe, ea4, csrc, cdst, pbt,
                                     eW1f + l * 48, eb1f + l * 16, w8);
    agg_k<<<12500, 256, 0, stream>>>(kv, w8, rst, csrc,
                                     lngf + l * 128, lnbf + l * 128, xf, xh);
    gemm_k<1><<<dim3(ROWT, 4), 256, 0, stream>>>(xh, W1t + (size_t)l * 65536, 128,
                                                 hb, nullptr, nullptr, fb1f + l * 512);
    gemm_k<2><<<dim3(ROWT, 1), 256, 0, stream>>>(hb, W2t + (size_t)l * 65536, 512,
                                                 ffh, nullptr, nullptr, fb2f + l * 128);
    ln_res_k<<<12500, 256, 0, stream>>>(ffh, xf, xh, lngf + l * 128, lnbf + l * 128);
  }
  out_k<<<25000, 256, 0, stream>>>(xf, d_out, dflag);
}

// Round 6
// 1406.448 us; speedup vs baseline: 1.2509x; 1.0788x over previous
//
#include <hip/hip_runtime.h>
#include <cstdint>
#include <cstddef>

#define NN 50000
#define NE 800000
#define NP 50048      // 391*128 padded rows
#define ROWT 391
#define NBLK 196      // ceil((NN+1)/256)

typedef unsigned short u16;
typedef _Float16 f16;
typedef _Float16 hf8 __attribute__((ext_vector_type(8)));
typedef float f32x4 __attribute__((ext_vector_type(4)));

union U32 { unsigned u; f16 h[2]; };
union U64 { uint2 v; f16 h[4]; };
union U128 { uint4 v; f16 x[8]; };

__device__ __forceinline__ float b2f(u16 v){ return __uint_as_float((unsigned)v << 16); }
__device__ __forceinline__ u16 f2b(float f){
  unsigned u = __float_as_uint(f);
  return (u16)((u + 0x7fffu + ((u >> 16) & 1u)) >> 16);
}
// dtype-agnostic load of float input i (flag: 1 = float32, 0 = bf16)
__device__ __forceinline__ float ldf(const void* p, long i, int f32){
  return f32 ? ((const float*)p)[i] : b2f(((const u16*)p)[i]);
}
__device__ __forceinline__ void gl_lds16(const void* g, void* l){
  __builtin_amdgcn_global_load_lds((const __attribute__((address_space(1))) void*)g,
                                   (__attribute__((address_space(3))) void*)l, 16, 0, 0);
}

// ---------------- dtype detect (bf16 N(0,1) has exp<=~0x81; f32 low-halves are random) ----
__global__ void detect_k(const u16* __restrict__ nf, int* __restrict__ flag)
{
  int mx = 0;
  for (int i = 0; i < 256; ++i) { int e = (nf[i] >> 7) & 0xFF; mx = e > mx ? e : mx; }
  flag[0] = (mx >= 0x90) ? 1 : 0;
}

__global__ void zero_i_k(int* __restrict__ p, int n)
{
  int i = blockIdx.x * 256 + threadIdx.x;
  if (i < n) p[i] = 0;
}

// ---------------- small-param f32 conversion table ----------------
// layout (floats): eW1[6*48]@0, eb1[6*16]@288, eb2[6*128]@384, lng[6*128]@1152,
// lnb[6*128]@1920, fb1[6*512]@2688, fb2[6*128]@5760, embB[128]@6528, embW[2560]@6656 ; total 9216
__global__ void conv_k(const void* eW1, const void* eb1, const void* eb2,
                       const void* lng, const void* lnb, const void* fb1, const void* fb2,
                       const void* embB, const void* embW,
                       float* __restrict__ pf, const int* __restrict__ dflag)
{
  int f32 = dflag[0];
  int i = blockIdx.x * 256 + threadIdx.x;
  if (i >= 9216) return;
  const void* p; long off;
  if (i < 288)       { p = eW1;  off = i; }
  else if (i < 384)  { p = eb1;  off = i - 288; }
  else if (i < 1152) { p = eb2;  off = i - 384; }
  else if (i < 1920) { p = lng;  off = i - 1152; }
  else if (i < 2688) { p = lnb;  off = i - 1920; }
  else if (i < 5760) { p = fb1;  off = i - 2688; }
  else if (i < 6528) { p = fb2;  off = i - 5760; }
  else if (i < 6656) { p = embB; off = i - 6528; }
  else               { p = embW; off = i - 6656; }
  pf[i] = ldf(p, off, f32);
}

// ---------------- weight prep ----------------
// Wcat[l] = [512 rows(n) x 128(k)] f16 : rows 0-127 Wq^T, 128-255 Wk^T, 256-383 Wv^T,
// rows 384-511 Wqe^T where Wqe[k][h*16+j] = sum_d Wq[k][h*16+d]*eW2[l][j][h*16+d]
__global__ void prep_qkve_k(const void* __restrict__ Wq, const void* __restrict__ Wk,
                            const void* __restrict__ Wv, const void* __restrict__ eW2,
                            f16* __restrict__ Wcat, const int* __restrict__ dflag)
{
  int f32 = dflag[0];
  int idx = blockIdx.x * 256 + threadIdx.x;   // [6][512][128]
  int l = idx >> 16;
  int rem = idx & 65535;
  int r = rem >> 7;
  int kk = rem & 127;
  long base = (long)l * 16384;
  float val;
  if (r < 384) {
    const void* W = (r < 128) ? Wq : (r < 256) ? Wk : Wv;
    int n = r & 127;
    val = ldf(W, base + kk * 128 + n, f32);
  } else {
    int n = r - 384, h = n >> 4, j = n & 15;
    long wq = base + kk * 128 + h * 16;
    long e2 = (long)l * 2048 + j * 128 + h * 16;
    float s = 0.f;
    #pragma unroll
    for (int d = 0; d < 16; ++d) s += ldf(Wq, wq + d, f32) * ldf(eW2, e2 + d, f32);
    val = s;
  }
  Wcat[idx] = (f16)val;
}

// in [6][R][C] -> out [6][C][R] f16 (B^T layout for gemm)
__global__ void transpose_k(const void* __restrict__ in, f16* __restrict__ out, int R, int C,
                            const int* __restrict__ dflag)
{
  int f32 = dflag[0];
  int idx = blockIdx.x * 256 + threadIdx.x;
  int rc = R * C;
  int l = idx / rc, rem = idx % rc;
  int r = rem / C, c = rem % C;
  out[l * rc + c * R + r] = (f16)ldf(in, idx, f32);
}

// ---------------- CSR build ----------------
__global__ void deg_count_k(const int* __restrict__ eidx, int* __restrict__ deg)
{
  int e = blockIdx.x * 256 + threadIdx.x;
  if (e < NE) atomicAdd(&deg[eidx[NE + e]], 1);
}

// hierarchical exclusive scan of deg[0..NN] -> rstart/cursor (3 tiny kernels)
__global__ void scan_a(const int* __restrict__ deg, int* __restrict__ bsum)
{
  __shared__ int tmp[256];
  int t = threadIdx.x, i = blockIdx.x * 256 + t;
  int v = (i < NN) ? deg[i] : 0;
  tmp[t] = v; __syncthreads();
  for (int o = 1; o < 256; o <<= 1) {
    int u = (t >= o) ? tmp[t - o] : 0;
    __syncthreads(); tmp[t] += u; __syncthreads();
  }
  if (t == 255) bsum[blockIdx.x] = tmp[255];
}

__global__ void scan_b(const int* __restrict__ bsum, int* __restrict__ boff) // 1 block x 256
{
  __shared__ int tmp[256];
  int t = threadIdx.x;
  int v = (t < NBLK) ? bsum[t] : 0;
  tmp[t] = v; __syncthreads();
  for (int o = 1; o < 256; o <<= 1) {
    int u = (t >= o) ? tmp[t - o] : 0;
    __syncthreads(); tmp[t] += u; __syncthreads();
  }
  if (t < NBLK) boff[t] = tmp[t] - v;  // exclusive
}

__global__ void scan_c(const int* __restrict__ deg, const int* __restrict__ boff,
                       int* __restrict__ rstart, int* __restrict__ cursor)
{
  __shared__ int tmp[256];
  int t = threadIdx.x, i = blockIdx.x * 256 + t;
  int v = (i < NN) ? deg[i] : 0;
  tmp[t] = v; __syncthreads();
  for (int o = 1; o < 256; o <<= 1) {
    int u = (t >= o) ? tmp[t - o] : 0;
    __syncthreads(); tmp[t] += u; __syncthreads();
  }
  if (i <= NN) {
    int ex = boff[blockIdx.x] + tmp[t] - v;
    rstart[i] = ex;
    if (i < NN) cursor[i] = ex;
  }
}

__global__ void csr_fill_k(const int* __restrict__ eidx, int* __restrict__ cursor,
                           int* __restrict__ csrc, int* __restrict__ cdst,
                           int* __restrict__ ceid)
{
  int e = blockIdx.x * 256 + threadIdx.x;
  if (e >= NE) return;
  int d = eidx[NE + e];
  int slot = atomicAdd(&cursor[d], 1);
  csrc[slot] = eidx[e];
  cdst[slot] = d;
  ceid[slot] = e;
}

// gather edge attrs into CSR slot order, 4 f16 per slot (8B aligned)
__global__ void ea_gather_k(const void* __restrict__ eatt, const int* __restrict__ ceid,
                            f16* __restrict__ ea4, const int* __restrict__ dflag)
{
  int f32 = dflag[0];
  int e = blockIdx.x * 256 + threadIdx.x;
  if (e >= NE) return;
  long id = ceid[e];
  f16* q = ea4 + (size_t)e * 4;
  q[0] = (f16)ldf(eatt, id * 3 + 0, f32);
  q[1] = (f16)ldf(eatt, id * 3 + 1, f32);
  q[2] = (f16)ldf(eatt, id * 3 + 2, f32);
  q[3] = (f16)0.f;
}

// ---------------- embedding (covers padded rows with zeros) ----------------
__global__ void emb_k(const void* __restrict__ nf, const float* __restrict__ embWf,
                      const float* __restrict__ embBf, float* __restrict__ xf,
                      f16* __restrict__ xh, const int* __restrict__ dflag)
{
  int f32 = dflag[0];
  int idx = blockIdx.x * 256 + threadIdx.x;   // NP*128 exact
  int node = idx >> 7, c = idx & 127;
  float s = 0.f;
  if (node < NN) {
    s = embBf[c];
    long row = (long)node * 20;
    #pragma unroll
    for (int f = 0; f < 20; ++f) s += ldf(nf, row + f, f32) * embWf[f * 128 + c];
  }
  xf[idx] = s;
  xh[idx] = (f16)s;
}

// ---------------- MFMA GEMM: C = A[M,K] @ B (given as Bt[N,K]), 128x128 tile, BK=64 ----------------
// global_load_lds width-16; issue i covers 8 contiguous rows (lane->row=lane>>3, chunk=lane&7),
// satisfying the wave-uniform-base + lane*16B scatter rule.
// MODE 0: q -> o0 (ld128), k -> o1 cols 0-127 of ld256, v -> o1 cols 128-255, qe -> o3. grid (391,4)
// MODE 1: f16 out (hb), ld 512, bias + relu. grid (391,4)
// MODE 2: f16 out (ffh), ld 128, bias. grid (391,1)
template<int MODE>
__global__ __launch_bounds__(256)
void gemm_k(const f16* __restrict__ A, const f16* __restrict__ Bt, int K,
            f16* __restrict__ o0, f16* __restrict__ o1, f16* __restrict__ o3,
            const float* __restrict__ bias)
{
  __shared__ __align__(16) f16 lA[128 * 64];
  __shared__ __align__(16) f16 lB[128 * 64];
  const int tid = threadIdx.x;
  const int wave = tid >> 6, lane = tid & 63;
  const int wr = wave >> 1, wc = wave & 1;
  const size_t rowBase = (size_t)blockIdx.x * 128;
  const size_t colBase = (size_t)blockIdx.y * 128;
  const int m = lane & 15, q4 = lane >> 4;

  f32x4 zero = {0.f, 0.f, 0.f, 0.f};
  f32x4 acc[4][4];
  #pragma unroll
  for (int i = 0; i < 4; ++i)
    #pragma unroll
    for (int j = 0; j < 4; ++j) acc[i][j] = zero;

  const int sr = lane >> 3, sc = lane & 7;   // staging: 8 lanes per row, 16B chunks
  const f16* Ap = A + (rowBase + wave * 32 + sr) * (size_t)K + sc * 8;
  const f16* Bp = Bt + (colBase + wave * 32 + sr) * (size_t)K + sc * 8;
  f16* lAp = lA + wave * 2048;   // wave's 32 rows x 64 f16
  f16* lBp = lB + wave * 2048;

  for (int k0 = 0; k0 < K; k0 += 64) {
    #pragma unroll
    for (int i = 0; i < 4; ++i) {
      gl_lds16(Ap + k0 + (size_t)(8 * i) * K, lAp + i * 512);
      gl_lds16(Bp + k0 + (size_t)(8 * i) * K, lBp + i * 512);
    }
    __syncthreads();
    hf8 af[2][4], bf[2][4];
    #pragma unroll
    for (int s = 0; s < 2; ++s)
      #pragma unroll
      for (int i = 0; i < 4; ++i) {
        af[s][i] = *(const hf8*)(lA + (wr * 64 + i * 16 + m) * 64 + s * 32 + q4 * 8);
        bf[s][i] = *(const hf8*)(lB + (wc * 64 + i * 16 + m) * 64 + s * 32 + q4 * 8);
      }
    #pragma unroll
    for (int s = 0; s < 2; ++s)
      #pragma unroll
      for (int i = 0; i < 4; ++i)
        #pragma unroll
        for (int j = 0; j < 4; ++j)
          acc[i][j] = __builtin_amdgcn_mfma_f32_16x16x32_f16(af[s][i], bf[s][j], acc[i][j], 0, 0, 0);
    __syncthreads();
  }

  // C/D layout: col = lane&15 (m), row = q4*4 + reg  (verified m89/m91)
  if (MODE == 0) {
    f16* o; size_t ld; int off;
    if (blockIdx.y == 0)      { o = o0; ld = 128; off = 0; }
    else if (blockIdx.y == 1) { o = o1; ld = 256; off = 0; }
    else if (blockIdx.y == 2) { o = o1; ld = 256; off = 128; }
    else                      { o = o3; ld = 128; off = 0; }
    #pragma unroll
    for (int i = 0; i < 4; ++i)
      #pragma unroll
      for (int r = 0; r < 4; ++r) {
        size_t row = rowBase + wr * 64 + i * 16 + q4 * 4 + r;
        #pragma unroll
        for (int j = 0; j < 4; ++j) {
          int col = wc * 64 + j * 16 + m;
          o[row * ld + off + col] = (f16)acc[i][j][r];
        }
      }
  } else if (MODE == 1) {
    #pragma unroll
    for (int j = 0; j < 4; ++j) {
      int colg = (int)colBase + wc * 64 + j * 16 + m;
      float bv = bias[colg];
      #pragma unroll
      for (int i = 0; i < 4; ++i)
        #pragma unroll
        for (int r = 0; r < 4; ++r) {
          size_t row = rowBase + wr * 64 + i * 16 + q4 * 4 + r;
          o0[row * 512 + colg] = (f16)fmaxf(acc[i][j][r] + bv, 0.f);
        }
    }
  } else {
    #pragma unroll
    for (int j = 0; j < 4; ++j) {
      int colg = wc * 64 + j * 16 + m;
      float bv = bias[colg];
      #pragma unroll
      for (int i = 0; i < 4; ++i)
        #pragma unroll
        for (int r = 0; r < 4; ++r) {
          size_t row = rowBase + wr * 64 + i * 16 + q4 * 4 + r;
          o0[row * 128 + colg] = (f16)(acc[i][j][r] + bv);
        }
    }
  }
}

// ---------------- per-(node,head) bias: pb = q . eb2 ----------------
__global__ void pb_k(const f16* __restrict__ qf, const float* __restrict__ eb2f,
                     float* __restrict__ pbt)
{
  int idx = blockIdx.x * 256 + threadIdx.x;
  if (idx >= NN * 8) return;
  int n = idx >> 3, h = idx & 7;
  U128 a, b;
  a.v = *(const uint4*)(qf + (size_t)n * 128 + h * 16);
  b.v = *(const uint4*)(qf + (size_t)n * 128 + h * 16 + 8);
  const float* e = eb2f + h * 16;
  float p = 0.f;
  #pragma unroll
  for (int d = 0; d < 8; ++d) p = fmaf((float)a.x[d], e[d], fmaf((float)b.x[d], e[8 + d], p));
  pbt[idx] = p;
}

// ---------------- edge-parallel attention weights: one LANE per edge ----------------
__global__ __launch_bounds__(256)
void attn_k(const f16* __restrict__ qf, const f16* __restrict__ kv, const f16* __restrict__ qef,
            const f16* __restrict__ ea4, const int* __restrict__ csrc, const int* __restrict__ cdst,
            const float* __restrict__ pbt, const float* __restrict__ eW1f,
            const float* __restrict__ eb1f, f16* __restrict__ w8)
{
  int e = blockIdx.x * 256 + threadIdx.x;
  if (e >= NE) return;
  int src = csrc[e], dst = cdst[e];
  U64 ue; ue.v = *(const uint2*)(ea4 + (size_t)e * 4);
  float a0 = (float)ue.h[0], a1 = (float)ue.h[1], a2 = (float)ue.h[2];
  float he[16];
  #pragma unroll
  for (int j = 0; j < 16; ++j)
    he[j] = fmaxf(fmaf(a2, eW1f[32 + j], fmaf(a1, eW1f[16 + j], fmaf(a0, eW1f[j], eb1f[j]))), 0.f);
  const uint4* qr = (const uint4*)(qf + (size_t)dst * 128);
  const uint4* kr = (const uint4*)(kv + (size_t)src * 256);
  const uint4* er = (const uint4*)(qef + (size_t)dst * 128);
  float4 pb0 = *(const float4*)(pbt + (size_t)dst * 8);
  float4 pb1 = *(const float4*)(pbt + (size_t)dst * 8 + 4);
  float pbv[8] = { pb0.x, pb0.y, pb0.z, pb0.w, pb1.x, pb1.y, pb1.z, pb1.w };
  float logit[8];
  uint4 qa = qr[0], qb = qr[1], ka = kr[0], kb = kr[1], za = er[0], zb = er[1];
  #pragma unroll
  for (int h = 0; h < 8; ++h) {
    uint4 qa2, qb2, ka2, kb2, za2, zb2;
    if (h < 7) {
      qa2 = qr[2*h+2]; qb2 = qr[2*h+3];
      ka2 = kr[2*h+2]; kb2 = kr[2*h+3];
      za2 = er[2*h+2]; zb2 = er[2*h+3];
    }
    U128 Q0, Q1, K0, K1, E0, E1;
    Q0.v = qa; Q1.v = qb; K0.v = ka; K1.v = kb; E0.v = za; E1.v = zb;
    float p = 0.f;
    #pragma unroll
    for (int d = 0; d < 8; ++d) {
      p = fmaf((float)Q0.x[d], (float)K0.x[d], p);
      p = fmaf((float)Q1.x[d], (float)K1.x[d], p);
      p = fmaf((float)E0.x[d], he[d], p);
      p = fmaf((float)E1.x[d], he[8 + d], p);
    }
    logit[h] = (p + pbv[h]) * 0.25f;
    qa = qa2; qb = qb2; ka = ka2; kb = kb2; za = za2; zb = zb2;
  }
  float mx = logit[0];
  #pragma unroll
  for (int h = 1; h < 8; ++h) mx = fmaxf(mx, logit[h]);
  float se = 0.f, ex[8];
  #pragma unroll
  for (int h = 0; h < 8; ++h) { ex[h] = __expf(logit[h] - mx); se += ex[h]; }
  float inv = 1.f / se;
  U128 W;
  #pragma unroll
  for (int h = 0; h < 8; ++h) W.x[h] = (f16)(ex[h] * inv);
  *(uint4*)(w8 + (size_t)e * 8) = W.v;
}

// ---------------- aggregation + residual + LN1 ----------------
__global__ void agg_k(const f16* __restrict__ kv, const f16* __restrict__ w8,
                      const int* __restrict__ rstart, const int* __restrict__ csrc,
                      const float* __restrict__ gf, const float* __restrict__ bpf,
                      float* __restrict__ xf, f16* __restrict__ xh)
{
  int wave = threadIdx.x >> 6, lane = threadIdx.x & 63;
  int node = blockIdx.x * 4 + wave;
  if (node >= NN) return;
  int sub = lane >> 4, l = lane & 15;
  int c0 = l << 3;
  int head = l >> 1;
  float acc[8] = {0.f, 0.f, 0.f, 0.f, 0.f, 0.f, 0.f, 0.f};
  int e0 = rstart[node], e1 = rstart[node + 1];
  int e = e0 + sub;
  uint4 vN = {0, 0, 0, 0}; float wN = 0.f;
  if (e < e1) {
    int s = csrc[e];
    vN = *(const uint4*)(kv + (size_t)s * 256 + 128 + c0);
    wN = (float)w8[(size_t)e * 8 + head];
  }
  for (; e < e1; e += 4) {
    uint4 vC = vN; float wC = wN;
    int en = e + 4;
    if (en < e1) {
      int s = csrc[en];
      vN = *(const uint4*)(kv + (size_t)s * 256 + 128 + c0);
      wN = (float)w8[(size_t)en * 8 + head];
    }
    U128 V; V.v = vC;
    #pragma unroll
    for (int i = 0; i < 8; ++i) acc[i] = fmaf(wC, (float)V.x[i], acc[i]);
  }
  #pragma unroll
  for (int i = 0; i < 8; ++i) {
    acc[i] += __shfl_xor(acc[i], 16);
    acc[i] += __shfl_xor(acc[i], 32);
  }
  size_t nb = (size_t)node * 128 + c0;
  float4 x0 = *(const float4*)(xf + nb);
  float4 x1 = *(const float4*)(xf + nb + 4);
  float y[8] = { x0.x + acc[0], x0.y + acc[1], x0.z + acc[2], x0.w + acc[3],
                 x1.x + acc[4], x1.y + acc[5], x1.z + acc[6], x1.w + acc[7] };
  float s1 = 0.f, s2 = 0.f;
  #pragma unroll
  for (int i = 0; i < 8; ++i) { s1 += y[i]; s2 += y[i] * y[i]; }
  #pragma unroll
  for (int o = 1; o < 16; o <<= 1) { s1 += __shfl_xor(s1, o); s2 += __shfl_xor(s2, o); }
  float mu = s1 * 0.0078125f;
  float var = s2 * 0.0078125f - mu * mu;
  float rstd = rsqrtf(var + 1e-5f);
  float ov[8];
  #pragma unroll
  for (int i = 0; i < 8; ++i) ov[i] = (y[i] - mu) * rstd * gf[c0 + i] + bpf[c0 + i];
  if (sub == 0) {
    float4 s0 = { ov[0], ov[1], ov[2], ov[3] };
    float4 s1v = { ov[4], ov[5], ov[6], ov[7] };
    *(float4*)(xf + nb) = s0;
    *(float4*)(xf + nb + 4) = s1v;
    U128 wz;
    #pragma unroll
    for (int i = 0; i < 8; ++i) wz.x[i] = (f16)ov[i];
    *(uint4*)(xh + nb) = wz.v;
  }
}

// ---------------- residual + LN2 (one wave per node) ----------------
__global__ void ln_res_k(const f16* __restrict__ add, float* __restrict__ xf,
                         f16* __restrict__ xh, const float* __restrict__ gf,
                         const float* __restrict__ bpf)
{
  int wave = threadIdx.x >> 6, lane = threadIdx.x & 63;
  int node = blockIdx.x * 4 + wave;
  if (node >= NN) return;
  int c0 = lane << 1;
  size_t nb = (size_t)node * 128 + c0;
  U32 ua; ua.u = *(const unsigned*)(add + nb);
  float y0 = xf[nb] + (float)ua.h[0];
  float y1 = xf[nb + 1] + (float)ua.h[1];
  float s1 = y0 + y1, s2 = y0 * y0 + y1 * y1;
  #pragma unroll
  for (int o = 1; o < 64; o <<= 1) { s1 += __shfl_xor(s1, o); s2 += __shfl_xor(s2, o); }
  float mu = s1 * 0.0078125f;
  float var = s2 * 0.0078125f - mu * mu;
  float rstd = rsqrtf(var + 1e-5f);
  float o0v = (y0 - mu) * rstd * gf[c0] + bpf[c0];
  float o1v = (y1 - mu) * rstd * gf[c0 + 1] + bpf[c0 + 1];
  xf[nb] = o0v; xf[nb + 1] = o1v;
  U32 wz; wz.h[0] = (f16)o0v; wz.h[1] = (f16)o1v;
  *(unsigned*)(xh + nb) = wz.u;
}

__global__ void out_k(const float* __restrict__ xf, void* __restrict__ out,
                      const int* __restrict__ dflag)
{
  int f32 = dflag[0];
  int idx = blockIdx.x * 256 + threadIdx.x;   // NN*128 exact
  if (f32) ((float*)out)[idx] = xf[idx];
  else     ((u16*)out)[idx] = f2b(xf[idx]);
}

// ---------------- launch ----------------
extern "C" void kernel_launch(void* const* d_in, const int* in_sizes, int n_in,
                              void* d_out, int out_size, void* d_ws, size_t ws_size,
                              hipStream_t stream)
{
  const void* nf   = d_in[0];
  const void* eatt = d_in[1];
  const int*  eidx = (const int*)d_in[2];
  const void* embW = d_in[3];
  const void* embB = d_in[4];
  const void* Wq   = d_in[5];
  const void* Wk   = d_in[6];
  const void* Wv   = d_in[7];
  const void* eW1  = d_in[8];
  const void* eb1  = d_in[9];
  const void* eW2  = d_in[10];
  const void* eb2  = d_in[11];
  const void* lng  = d_in[12];
  const void* lnb  = d_in[13];
  const void* fW1  = d_in[14];
  const void* fb1  = d_in[15];
  const void* fW2  = d_in[16];
  const void* fb2  = d_in[17];

  char* p = (char*)d_ws;
  auto alloc = [&](size_t b) { char* r = p; p += (b + 255) & ~(size_t)255; return r; };
  int* dflag   = (int*)alloc(256);
  float* pf    = (float*)alloc(9216 * 4);
  float* xf    = (float*)alloc((size_t)NP * 128 * 4);
  f16*   xh    = (f16*)  alloc((size_t)NP * 128 * 2);
  int* deg     = (int*)alloc((NN + 1) * 4);
  int* rst     = (int*)alloc((NN + 1) * 4);
  int* cur     = (int*)alloc((size_t)NN * 4);
  int* bsum    = (int*)alloc(NBLK * 4);
  int* boff    = (int*)alloc(NBLK * 4);
  int* csrc    = (int*)alloc((size_t)NE * 4);
  int* cdst    = (int*)alloc((size_t)NE * 4);
  float* pbt   = (float*)alloc((size_t)NN * 8 * 4);
  f16* ea4     = (f16*)alloc((size_t)NE * 4 * 2);
  f16* Wcat    = (f16*)alloc((size_t)6 * 512 * 128 * 2);
  f16* W1t     = (f16*)alloc((size_t)6 * 512 * 128 * 2);
  f16* W2t     = (f16*)alloc((size_t)6 * 128 * 512 * 2);
  // layer scratch S: edge phase = qf + qe + kv + w8(in ffh slot); ff phase = hb + ffh
  char* S    = alloc((size_t)NP * 512 * 2 + (size_t)NP * 128 * 2);
  f16* qf  = (f16*)S;
  f16* qe  = qf + (size_t)NP * 128;
  f16* kv  = qe + (size_t)NP * 128;   // [node][256]: k cols 0-127, v cols 128-255
  f16* hb  = (f16*)S;
  f16* ffh = hb + (size_t)NP * 512;
  f16* w8  = ffh;                      // NE*8 f16, disjoint in time from ffh use
  int* ceid = (int*)S;                 // build phase only

  float* eW1f = pf;          // +l*48
  float* eb1f = pf + 288;    // +l*16
  float* eb2f = pf + 384;    // +l*128
  float* lngf = pf + 1152;   // +l*128
  float* lnbf = pf + 1920;   // +l*128
  float* fb1f = pf + 2688;   // +l*512
  float* fb2f = pf + 5760;   // +l*128
  float* embBf = pf + 6528;
  float* embWf = pf + 6656;

  detect_k<<<1, 1, 0, stream>>>((const u16*)nf, dflag);
  conv_k<<<36, 256, 0, stream>>>(eW1, eb1, eb2, lng, lnb, fb1, fb2, embB, embW, pf, dflag);
  prep_qkve_k<<<1536, 256, 0, stream>>>(Wq, Wk, Wv, eW2, Wcat, dflag);
  transpose_k<<<1536, 256, 0, stream>>>(fW1, W1t, 128, 512, dflag);
  transpose_k<<<1536, 256, 0, stream>>>(fW2, W2t, 512, 128, dflag);
  zero_i_k<<<(NN + 256) / 256, 256, 0, stream>>>(deg, NN + 1);
  deg_count_k<<<3125, 256, 0, stream>>>(eidx, deg);
  scan_a<<<NBLK, 256, 0, stream>>>(deg, bsum);
  scan_b<<<1, 256, 0, stream>>>(bsum, boff);
  scan_c<<<NBLK, 256, 0, stream>>>(deg, boff, rst, cur);
  csr_fill_k<<<3125, 256, 0, stream>>>(eidx, cur, csrc, cdst, ceid);
  ea_gather_k<<<3125, 256, 0, stream>>>(eatt, ceid, ea4, dflag);
  emb_k<<<NP * 128 / 256, 256, 0, stream>>>(nf, embWf, embBf, xf, xh, dflag);

  for (int l = 0; l < 6; ++l) {
    gemm_k<0><<<dim3(ROWT, 4), 256, 0, stream>>>(xh, Wcat + (size_t)l * 65536, 128,
                                                 qf, kv, qe, nullptr);
    pb_k<<<(NN * 8 + 255) / 256, 256, 0, stream>>>(qf, eb2f + l * 128, pbt);
    attn_k<<<3125, 256, 0, stream>>>(qf, kv, qe, ea4, csrc, cdst, pbt,
                                     eW1f + l * 48, eb1f + l * 16, w8);
    agg_k<<<12500, 256, 0, stream>>>(kv, w8, rst, csrc,
                                     lngf + l * 128, lnbf + l * 128, xf, xh);
    gemm_k<1><<<dim3(ROWT, 4), 256, 0, stream>>>(xh, W1t + (size_t)l * 65536, 128,
                                                 hb, nullptr, nullptr, fb1f + l * 512);
    gemm_k<2><<<dim3(ROWT, 1), 256, 0, stream>>>(hb, W2t + (size_t)l * 65536, 512,
                                                 ffh, nullptr, nullptr, fb2f + l * 128);
    ln_res_k<<<12500, 256, 0, stream>>>(ffh, xf, xh, lngf + l * 128, lnbf + l * 128);
  }
  out_k<<<25000, 256, 0, stream>>>(xf, d_out, dflag);
}